// Round 1
// baseline (384.164 us; speedup 1.0000x reference)
//
#include <hip/hip_runtime.h>

#define B_ 2
#define S_ 2048
#define D_ 1024
#define H_ 16
#define HD_ 64
#define M_ (B_ * S_)  // 4096

typedef __bf16 bf16x8 __attribute__((ext_vector_type(8)));
typedef float f32x4 __attribute__((ext_vector_type(4)));

__device__ inline unsigned short f2bf(float f) {
    unsigned int u = __builtin_bit_cast(unsigned int, f);
    u += 0x7fffu + ((u >> 16) & 1u);
    return (unsigned short)(u >> 16);
}

// ---------------- f32 -> bf16 convert ----------------
__global__ __launch_bounds__(256) void cvt_kernel(const float* __restrict__ in,
                                                  unsigned short* __restrict__ out, int n) {
    int i = (blockIdx.x * 256 + threadIdx.x) * 4;
    if (i + 3 < n) {
        float4 v = *(const float4*)(in + i);
        ushort4 o;
        o.x = f2bf(v.x); o.y = f2bf(v.y); o.z = f2bf(v.z); o.w = f2bf(v.w);
        *(ushort4*)(out + i) = o;
    }
}

// ---------------- shared GEMM core: C[128x128] = A[M,K] @ W[N,K]^T ----------------
// A row-major [M,K] bf16, W row-major [N,K] bf16 (both K-contiguous).
// 256 threads = 4 waves in 2x2; each wave owns a 64x64 strip (4x4 tiles of 16x16).
__device__ inline void gemm_compute(const unsigned short* __restrict__ A,
                                    const unsigned short* __restrict__ W,
                                    int K, int m0, int n0,
                                    unsigned short* As, unsigned short* Bs,
                                    f32x4 acc[4][4]) {
    const int t = threadIdx.x;
    const int lane = t & 63, wave = t >> 6;
    const int ml = lane & 15, quad = lane >> 4;
    const int wr = (wave >> 1) * 64, wc = (wave & 1) * 64;
    const int r = t >> 3, c8 = (t & 7) << 3;

    const f32x4 zero = {0.f, 0.f, 0.f, 0.f};
    for (int i = 0; i < 4; i++)
        for (int j = 0; j < 4; j++) acc[i][j] = zero;

    for (int kt = 0; kt < K; kt += 64) {
        for (int rr = 0; rr < 128; rr += 32) {
            *(uint4*)(As + (r + rr) * 72 + c8) =
                *(const uint4*)(A + (size_t)(m0 + r + rr) * K + kt + c8);
            *(uint4*)(Bs + (r + rr) * 72 + c8) =
                *(const uint4*)(W + (size_t)(n0 + r + rr) * K + kt + c8);
        }
        __syncthreads();
        for (int kk = 0; kk < 2; ++kk) {
            bf16x8 af[4], bfr[4];
            for (int i = 0; i < 4; i++)
                af[i] = *(const bf16x8*)(As + (wr + i * 16 + ml) * 72 + kk * 32 + quad * 8);
            for (int j = 0; j < 4; j++)
                bfr[j] = *(const bf16x8*)(Bs + (wc + j * 16 + ml) * 72 + kk * 32 + quad * 8);
            for (int i = 0; i < 4; i++)
                for (int j = 0; j < 4; j++)
                    acc[i][j] = __builtin_amdgcn_mfma_f32_16x16x32_bf16(af[i], bfr[j], acc[i][j], 0, 0, 0);
        }
        __syncthreads();
    }
}

// ---------------- QKV projection (z selects q/k/v), head-split bf16 epilogue ----------------
__global__ __launch_bounds__(256) void gemm_qkv(
    const unsigned short* __restrict__ xq, const unsigned short* __restrict__ xk,
    const unsigned short* __restrict__ xv,
    const unsigned short* __restrict__ wq, const unsigned short* __restrict__ wk,
    const unsigned short* __restrict__ wv,
    const float* __restrict__ bq, const float* __restrict__ bk, const float* __restrict__ bv,
    unsigned short* __restrict__ oq, unsigned short* __restrict__ ok,
    unsigned short* __restrict__ ov) {
    __shared__ unsigned short As[128 * 72], Bs[128 * 72];
    const unsigned short *A, *W;
    const float* bias;
    unsigned short* out;
    int z = blockIdx.z;
    if (z == 0) { A = xq; W = wq; bias = bq; out = oq; }
    else if (z == 1) { A = xk; W = wk; bias = bk; out = ok; }
    else { A = xv; W = wv; bias = bv; out = ov; }

    int m0 = blockIdx.y * 128, n0 = blockIdx.x * 128;
    f32x4 acc[4][4];
    gemm_compute(A, W, D_, m0, n0, As, Bs, acc);

    const int t = threadIdx.x, lane = t & 63, wave = t >> 6;
    const int ml = lane & 15, quad = lane >> 4;
    const int wr = (wave >> 1) * 64, wc = (wave & 1) * 64;
    for (int i = 0; i < 4; i++)
        for (int j = 0; j < 4; j++) {
            int n = n0 + wc + j * 16 + ml;
            float bb = bias[n];
            int h = n >> 6, d = n & 63;
            for (int rg = 0; rg < 4; rg++) {
                int m = m0 + wr + i * 16 + quad * 4 + rg;
                int b = m >> 11, s = m & 2047;
                out[(((size_t)(b * H_ + h)) * S_ + s) * 64 + d] = f2bf(acc[i][j][rg] + bb);
            }
        }
}

// ---------------- output projection, f32 epilogue ----------------
__global__ __launch_bounds__(256) void gemm_out(const unsigned short* __restrict__ A,
                                                const unsigned short* __restrict__ W,
                                                const float* __restrict__ bias,
                                                float* __restrict__ out) {
    __shared__ unsigned short As[128 * 72], Bs[128 * 72];
    int m0 = blockIdx.y * 128, n0 = blockIdx.x * 128;
    f32x4 acc[4][4];
    gemm_compute(A, W, D_, m0, n0, As, Bs, acc);

    const int t = threadIdx.x, lane = t & 63, wave = t >> 6;
    const int ml = lane & 15, quad = lane >> 4;
    const int wr = (wave >> 1) * 64, wc = (wave & 1) * 64;
    for (int i = 0; i < 4; i++)
        for (int j = 0; j < 4; j++) {
            int n = n0 + wc + j * 16 + ml;
            float bb = bias[n];
            for (int rg = 0; rg < 4; rg++) {
                int m = m0 + wr + i * 16 + quad * 4 + rg;
                out[(size_t)m * D_ + n] = acc[i][j][rg] + bb;
            }
        }
}

// ---------------- flash attention, causal ----------------
// grid (S/64, B*H); 4 waves x 16 q-rows each. qh/kh/vh: bf16 [B,H,S,64].
// ctx out: bf16 merged [B,S,D].
__global__ __launch_bounds__(256) void attn_kernel(const unsigned short* __restrict__ qh,
                                                   const unsigned short* __restrict__ kh,
                                                   const unsigned short* __restrict__ vh,
                                                   unsigned short* __restrict__ ctx) {
    __shared__ unsigned short Ks[64 * 72];   // K tile [ki][d]
    __shared__ unsigned short Vt[64 * 72];   // V tile transposed [d][ki]
    __shared__ unsigned short Ps[64 * 72];   // P strips, 16 rows per wave

    const int qt = blockIdx.x, bh = blockIdx.y;
    const size_t base = (size_t)bh * S_ * 64;
    const int t = threadIdx.x, lane = t & 63, wave = t >> 6;
    const int ml = lane & 15, quad = lane >> 4;

    // Q fragments (A-layout), persistent across k-tiles
    bf16x8 qf[2];
    {
        int qrow = qt * 64 + wave * 16 + ml;
        qf[0] = *(const bf16x8*)(qh + base + (size_t)qrow * 64 + quad * 8);
        qf[1] = *(const bf16x8*)(qh + base + (size_t)qrow * 64 + 32 + quad * 8);
    }

    const f32x4 zero = {0.f, 0.f, 0.f, 0.f};
    f32x4 acc[4];
    for (int j = 0; j < 4; j++) acc[j] = zero;
    float m_i[4], l_i[4];
    for (int rg = 0; rg < 4; rg++) { m_i[rg] = -INFINITY; l_i[rg] = 0.f; }

    const int r = t >> 3, c8 = (t & 7) << 3;

    for (int kt = 0; kt <= qt; ++kt) {
        // stage K tile and transposed V tile
        for (int rr = 0; rr < 64; rr += 32) {
            int ki = rr + r;
            *(uint4*)(Ks + ki * 72 + c8) =
                *(const uint4*)(kh + base + (size_t)(kt * 64 + ki) * 64 + c8);
            uint4 vv = *(const uint4*)(vh + base + (size_t)(kt * 64 + ki) * 64 + c8);
            unsigned short vs[8];
            *(uint4*)vs = vv;
            for (int jj = 0; jj < 8; jj++) Vt[(c8 + jj) * 72 + ki] = vs[jj];
        }
        __syncthreads();

        // S = Q K^T (each wave: 16 q-rows x 64 ki)
        f32x4 sacc[4];
        for (int n = 0; n < 4; n++) sacc[n] = zero;
        for (int n = 0; n < 4; n++)
            for (int kk = 0; kk < 2; kk++) {
                bf16x8 kf = *(const bf16x8*)(Ks + (n * 16 + ml) * 72 + kk * 32 + quad * 8);
                sacc[n] = __builtin_amdgcn_mfma_f32_16x16x32_bf16(qf[kk], kf, sacc[n], 0, 0, 0);
            }

        // scale + causal mask (diagonal tile only)
        const float scl = 0.125f;  // 1/sqrt(64)
        for (int n = 0; n < 4; n++)
            for (int rg = 0; rg < 4; rg++) {
                float sv = sacc[n][rg] * scl;
                if (kt == qt) {
                    int kidx = n * 16 + ml;
                    int qidx = wave * 16 + quad * 4 + rg;
                    if (kidx > qidx) sv = -3.0e38f;
                }
                sacc[n][rg] = sv;
            }

        // online softmax: row max over 64 cols (4 tiles x 16 lanes of quad)
        float alpha[4];
        for (int rg = 0; rg < 4; rg++) {
            float v = fmaxf(fmaxf(sacc[0][rg], sacc[1][rg]), fmaxf(sacc[2][rg], sacc[3][rg]));
            for (int msk = 1; msk < 16; msk <<= 1) v = fmaxf(v, __shfl_xor(v, msk));
            float mo = m_i[rg];
            float mc = fmaxf(mo, v);
            alpha[rg] = __expf(mo - mc);
            m_i[rg] = mc;
        }
        float rsum[4] = {0.f, 0.f, 0.f, 0.f};
        for (int n = 0; n < 4; n++)
            for (int rg = 0; rg < 4; rg++) {
                float p = __expf(sacc[n][rg] - m_i[rg]);
                sacc[n][rg] = p;
                rsum[rg] += p;
            }
        for (int rg = 0; rg < 4; rg++) {
            float v = rsum[rg];
            for (int msk = 1; msk < 16; msk <<= 1) v += __shfl_xor(v, msk);
            l_i[rg] = l_i[rg] * alpha[rg] + v;
            for (int j = 0; j < 4; j++) acc[j][rg] *= alpha[rg];
        }

        // P (C-layout) -> LDS -> A-layout
        for (int n = 0; n < 4; n++)
            for (int rg = 0; rg < 4; rg++)
                Ps[(wave * 16 + quad * 4 + rg) * 72 + n * 16 + ml] = f2bf(sacc[n][rg]);

        // ctx += P V  (V^T in LDS gives contiguous B-operand reads)
        for (int j = 0; j < 4; j++)
            for (int kk = 0; kk < 2; kk++) {
                bf16x8 pf = *(const bf16x8*)(Ps + (wave * 16 + ml) * 72 + kk * 32 + quad * 8);
                bf16x8 vf = *(const bf16x8*)(Vt + (j * 16 + ml) * 72 + kk * 32 + quad * 8);
                acc[j] = __builtin_amdgcn_mfma_f32_16x16x32_bf16(pf, vf, acc[j], 0, 0, 0);
            }
        __syncthreads();
    }

    // epilogue: ctx merged [B,S,D] bf16
    int b = bh >> 4, h = bh & 15;
    for (int j = 0; j < 4; j++) {
        int d = j * 16 + ml;
        for (int rg = 0; rg < 4; rg++) {
            int srow = qt * 64 + wave * 16 + quad * 4 + rg;
            float val = acc[j][rg] / l_i[rg];
            ctx[((size_t)(b * S_ + srow)) * D_ + h * 64 + d] = f2bf(val);
        }
    }
}

extern "C" void kernel_launch(void* const* d_in, const int* in_sizes, int n_in,
                              void* d_out, int out_size, void* d_ws, size_t ws_size,
                              hipStream_t stream) {
    const float* query = (const float*)d_in[0];
    const float* key_ = (const float*)d_in[1];
    const float* value = (const float*)d_in[2];
    // d_in[3] = mask: known causal, handled in-kernel
    const float* Wq = (const float*)d_in[4];
    const float* bq = (const float*)d_in[5];
    const float* Wk = (const float*)d_in[6];
    const float* bk = (const float*)d_in[7];
    const float* Wv = (const float*)d_in[8];
    const float* bv = (const float*)d_in[9];
    const float* Wo = (const float*)d_in[10];
    const float* bo = (const float*)d_in[11];
    float* out = (float*)d_out;

    const size_t XE = (size_t)M_ * D_;  // 4,194,304
    const size_t WE = (size_t)D_ * D_;  // 1,048,576
    char* ws = (char*)d_ws;
    unsigned short* xq = (unsigned short*)ws; ws += XE * 2;
    unsigned short* xk = (unsigned short*)ws; ws += XE * 2;
    unsigned short* xv = (unsigned short*)ws; ws += XE * 2;
    unsigned short* wqb = (unsigned short*)ws; ws += WE * 2;
    unsigned short* wkb = (unsigned short*)ws; ws += WE * 2;
    unsigned short* wvb = (unsigned short*)ws; ws += WE * 2;
    unsigned short* wob = (unsigned short*)ws; ws += WE * 2;
    unsigned short* qh = (unsigned short*)ws; ws += XE * 2;
    unsigned short* kh = (unsigned short*)ws; ws += XE * 2;
    unsigned short* vh = (unsigned short*)ws; ws += XE * 2;
    unsigned short* ctx = (unsigned short*)ws; ws += XE * 2;

    // f32 -> bf16 conversions
    cvt_kernel<<<XE / 1024, 256, 0, stream>>>(query, xq, (int)XE);
    cvt_kernel<<<XE / 1024, 256, 0, stream>>>(key_, xk, (int)XE);
    cvt_kernel<<<XE / 1024, 256, 0, stream>>>(value, xv, (int)XE);
    cvt_kernel<<<WE / 1024, 256, 0, stream>>>(Wq, wqb, (int)WE);
    cvt_kernel<<<WE / 1024, 256, 0, stream>>>(Wk, wkb, (int)WE);
    cvt_kernel<<<WE / 1024, 256, 0, stream>>>(Wv, wvb, (int)WE);
    cvt_kernel<<<WE / 1024, 256, 0, stream>>>(Wo, wob, (int)WE);

    // QKV projections (fused launch, z = which)
    gemm_qkv<<<dim3(D_ / 128, M_ / 128, 3), 256, 0, stream>>>(
        xq, xk, xv, wqb, wkb, wvb, bq, bk, bv, qh, kh, vh);

    // causal flash attention
    attn_kernel<<<dim3(S_ / 64, B_ * H_), 256, 0, stream>>>(qh, kh, vh, ctx);

    // output projection
    gemm_out<<<dim3(D_ / 128, M_ / 128), 256, 0, stream>>>(ctx, wob, bo, out);
}

// Round 2
// 373.867 us; speedup vs baseline: 1.0275x; 1.0275x over previous
//
#include <hip/hip_runtime.h>

#define B_ 2
#define S_ 2048
#define D_ 1024
#define H_ 16
#define HD_ 64
#define M_ (B_ * S_)  // 4096

typedef __bf16 bf16x8 __attribute__((ext_vector_type(8)));
typedef float f32x4 __attribute__((ext_vector_type(4)));

__device__ inline unsigned short f2bf(float f) {
    unsigned int u = __builtin_bit_cast(unsigned int, f);
    u += 0x7fffu + ((u >> 16) & 1u);
    return (unsigned short)(u >> 16);
}

// ---------------- f32 -> bf16 convert ----------------
__global__ __launch_bounds__(256) void cvt_kernel(const float* __restrict__ in,
                                                  unsigned short* __restrict__ out, int n) {
    int i = (blockIdx.x * 256 + threadIdx.x) * 4;
    if (i + 3 < n) {
        float4 v = *(const float4*)(in + i);
        ushort4 o;
        o.x = f2bf(v.x); o.y = f2bf(v.y); o.z = f2bf(v.z); o.w = f2bf(v.w);
        *(ushort4*)(out + i) = o;
    }
}

// ---------------- shared GEMM core: C[128x128] = A[M,K] @ W[N,K]^T ----------------
__device__ inline void gemm_compute(const unsigned short* __restrict__ A,
                                    const unsigned short* __restrict__ W,
                                    int K, int m0, int n0,
                                    unsigned short* As, unsigned short* Bs,
                                    f32x4 acc[4][4]) {
    const int t = threadIdx.x;
    const int lane = t & 63, wave = t >> 6;
    const int ml = lane & 15, quad = lane >> 4;
    const int wr = (wave >> 1) * 64, wc = (wave & 1) * 64;
    const int r = t >> 3, c8 = (t & 7) << 3;

    const f32x4 zero = {0.f, 0.f, 0.f, 0.f};
    for (int i = 0; i < 4; i++)
        for (int j = 0; j < 4; j++) acc[i][j] = zero;

    for (int kt = 0; kt < K; kt += 64) {
        for (int rr = 0; rr < 128; rr += 32) {
            *(uint4*)(As + (r + rr) * 72 + c8) =
                *(const uint4*)(A + (size_t)(m0 + r + rr) * K + kt + c8);
            *(uint4*)(Bs + (r + rr) * 72 + c8) =
                *(const uint4*)(W + (size_t)(n0 + r + rr) * K + kt + c8);
        }
        __syncthreads();
        for (int kk = 0; kk < 2; ++kk) {
            bf16x8 af[4], bfr[4];
            for (int i = 0; i < 4; i++)
                af[i] = *(const bf16x8*)(As + (wr + i * 16 + ml) * 72 + kk * 32 + quad * 8);
            for (int j = 0; j < 4; j++)
                bfr[j] = *(const bf16x8*)(Bs + (wc + j * 16 + ml) * 72 + kk * 32 + quad * 8);
            for (int i = 0; i < 4; i++)
                for (int j = 0; j < 4; j++)
                    acc[i][j] = __builtin_amdgcn_mfma_f32_16x16x32_bf16(af[i], bfr[j], acc[i][j], 0, 0, 0);
        }
        __syncthreads();
    }
}

// ---------------- QKV projection (z selects q/k/v), head-split bf16 epilogue ----------------
__global__ __launch_bounds__(256) void gemm_qkv(
    const unsigned short* __restrict__ xq, const unsigned short* __restrict__ xk,
    const unsigned short* __restrict__ xv,
    const unsigned short* __restrict__ wq, const unsigned short* __restrict__ wk,
    const unsigned short* __restrict__ wv,
    const float* __restrict__ bq, const float* __restrict__ bk, const float* __restrict__ bv,
    unsigned short* __restrict__ oq, unsigned short* __restrict__ ok,
    unsigned short* __restrict__ ov) {
    __shared__ unsigned short As[128 * 72], Bs[128 * 72];
    const unsigned short *A, *W;
    const float* bias;
    unsigned short* out;
    int z = blockIdx.z;
    if (z == 0) { A = xq; W = wq; bias = bq; out = oq; }
    else if (z == 1) { A = xk; W = wk; bias = bk; out = ok; }
    else { A = xv; W = wv; bias = bv; out = ov; }

    int m0 = blockIdx.y * 128, n0 = blockIdx.x * 128;
    f32x4 acc[4][4];
    gemm_compute(A, W, D_, m0, n0, As, Bs, acc);

    const int t = threadIdx.x, lane = t & 63, wave = t >> 6;
    const int ml = lane & 15, quad = lane >> 4;
    const int wr = (wave >> 1) * 64, wc = (wave & 1) * 64;
    for (int i = 0; i < 4; i++)
        for (int j = 0; j < 4; j++) {
            int n = n0 + wc + j * 16 + ml;
            float bb = bias[n];
            int h = n >> 6, d = n & 63;
            for (int rg = 0; rg < 4; rg++) {
                int m = m0 + wr + i * 16 + quad * 4 + rg;
                int b = m >> 11, s = m & 2047;
                out[(((size_t)(b * H_ + h)) * S_ + s) * 64 + d] = f2bf(acc[i][j][rg] + bb);
            }
        }
}

// ---------------- output projection, f32 epilogue ----------------
__global__ __launch_bounds__(256) void gemm_out(const unsigned short* __restrict__ A,
                                                const unsigned short* __restrict__ W,
                                                const float* __restrict__ bias,
                                                float* __restrict__ out) {
    __shared__ unsigned short As[128 * 72], Bs[128 * 72];
    int m0 = blockIdx.y * 128, n0 = blockIdx.x * 128;
    f32x4 acc[4][4];
    gemm_compute(A, W, D_, m0, n0, As, Bs, acc);

    const int t = threadIdx.x, lane = t & 63, wave = t >> 6;
    const int ml = lane & 15, quad = lane >> 4;
    const int wr = (wave >> 1) * 64, wc = (wave & 1) * 64;
    for (int i = 0; i < 4; i++)
        for (int j = 0; j < 4; j++) {
            int n = n0 + wc + j * 16 + ml;
            float bb = bias[n];
            for (int rg = 0; rg < 4; rg++) {
                int m = m0 + wr + i * 16 + quad * 4 + rg;
                out[(size_t)m * D_ + n] = acc[i][j][rg] + bb;
            }
        }
}

// ---------------- flash attention, causal, load-balanced ----------------
// grid (8, B*H). Block handles q-blocks {slot, 15-slot} (128 rows each) -> 34 k-tiles/block.
// 4 waves; wave owns strips {wave*16, 64+wave*16} within the q-block.
// Double-buffered K/V staging; V transposed into LDS with pad-72 + chunk XOR swizzle.
__global__ __launch_bounds__(256, 1) void attn_kernel(const unsigned short* __restrict__ qh,
                                                      const unsigned short* __restrict__ kh,
                                                      const unsigned short* __restrict__ vh,
                                                      unsigned short* __restrict__ ctx) {
    __shared__ unsigned short Ks[2][64 * 72];
    __shared__ unsigned short Vs[2][64 * 72];  // transposed [d][k], swizzled
    __shared__ unsigned short Ps[128 * 72];

    const int slot = blockIdx.x, bh = blockIdx.y;
    const size_t base = (size_t)bh * S_ * 64;
    const int t = threadIdx.x, lane = t & 63, wave = t >> 6;
    const int ml = lane & 15, quad = lane >> 4;
    const int lr = t >> 3, lc8 = (t & 7) << 3;  // staging coords: row t>>3 (+0/32), col chunk

    const f32x4 zero = {0.f, 0.f, 0.f, 0.f};

    for (int qi = 0; qi < 2; qi++) {
        const int qb = qi ? (15 - slot) : slot;
        const int q0 = qb * 128;

        // persistent Q fragments for both strips
        bf16x8 qf[2][2];
        for (int mt = 0; mt < 2; mt++) {
            int qrow = q0 + mt * 64 + wave * 16 + ml;
            qf[mt][0] = *(const bf16x8*)(qh + base + (size_t)qrow * 64 + quad * 8);
            qf[mt][1] = *(const bf16x8*)(qh + base + (size_t)qrow * 64 + 32 + quad * 8);
        }

        f32x4 acc[2][4];
        float m_i[2][4], l_i[2][4];
        for (int mt = 0; mt < 2; mt++)
            for (int rg = 0; rg < 4; rg++) {
                acc[mt][0] = zero; acc[mt][1] = zero; acc[mt][2] = zero; acc[mt][3] = zero;
                m_i[mt][rg] = -INFINITY; l_i[mt][rg] = 0.f;
            }

        const int nkt = 2 * qb + 2;

        // stage kt=0 into buffer 0
        for (int pass = 0; pass < 2; pass++) {
            int ki = pass * 32 + lr;
            *(uint4*)(Ks[0] + ki * 72 + lc8) =
                *(const uint4*)(kh + base + (size_t)ki * 64 + lc8);
            uint4 vv = *(const uint4*)(vh + base + (size_t)ki * 64 + lc8);
            unsigned short vs[8];
            *(uint4*)vs = vv;
            for (int jj = 0; jj < 8; jj++) {
                int d = lc8 + jj;
                Vs[0][d * 72 + ((((ki >> 3) ^ (d >> 3)) & 7) << 3) + (ki & 7)] = vs[jj];
            }
        }
        __syncthreads();

        for (int kt = 0; kt < nkt; kt++) {
            const int buf = kt & 1;
            const bool pre = (kt + 1 < nkt);
            uint4 krg[2], vrg[2];
            if (pre) {
                int krow = (kt + 1) * 64;
                for (int pass = 0; pass < 2; pass++) {
                    int ki = pass * 32 + lr;
                    krg[pass] = *(const uint4*)(kh + base + (size_t)(krow + ki) * 64 + lc8);
                    vrg[pass] = *(const uint4*)(vh + base + (size_t)(krow + ki) * 64 + lc8);
                }
            }

            // hoisted K and V fragments (reused by both strips)
            bf16x8 kf[4][2], vf[4][2];
            for (int n = 0; n < 4; n++)
                for (int kk = 0; kk < 2; kk++)
                    kf[n][kk] = *(const bf16x8*)(Ks[buf] + (n * 16 + ml) * 72 + kk * 32 + quad * 8);
            for (int j = 0; j < 4; j++)
                for (int kk = 0; kk < 2; kk++) {
                    int d = j * 16 + ml;
                    vf[j][kk] = *(const bf16x8*)(Vs[buf] + d * 72 +
                                                 ((((kk * 4 + quad) ^ (d >> 3)) & 7) << 3));
                }

            for (int mt = 0; mt < 2; mt++) {
                const int qlo = q0 + mt * 64 + wave * 16;
                if (kt * 64 >= qlo + 16) continue;  // strip fully masked

                f32x4 sacc[4];
                for (int n = 0; n < 4; n++) sacc[n] = zero;
                for (int n = 0; n < 4; n++)
                    for (int kk = 0; kk < 2; kk++)
                        sacc[n] = __builtin_amdgcn_mfma_f32_16x16x32_bf16(qf[mt][kk], kf[n][kk], sacc[n], 0, 0, 0);

                const float scl = 0.125f;
                const bool full = (kt * 64 + 63 <= qlo);
                for (int n = 0; n < 4; n++)
                    for (int rg = 0; rg < 4; rg++) {
                        float sv = sacc[n][rg] * scl;
                        if (!full) {
                            int kidx = kt * 64 + n * 16 + ml;
                            int qidx = qlo + quad * 4 + rg;
                            if (kidx > qidx) sv = -3.0e38f;
                        }
                        sacc[n][rg] = sv;
                    }

                float alpha[4];
                for (int rg = 0; rg < 4; rg++) {
                    float v = fmaxf(fmaxf(sacc[0][rg], sacc[1][rg]), fmaxf(sacc[2][rg], sacc[3][rg]));
                    for (int msk = 1; msk < 16; msk <<= 1) v = fmaxf(v, __shfl_xor(v, msk));
                    float mo = m_i[mt][rg];
                    float mc = fmaxf(mo, v);
                    alpha[rg] = __expf(mo - mc);
                    m_i[mt][rg] = mc;
                }
                float rsum[4] = {0.f, 0.f, 0.f, 0.f};
                for (int n = 0; n < 4; n++)
                    for (int rg = 0; rg < 4; rg++) {
                        float p = __expf(sacc[n][rg] - m_i[mt][rg]);
                        sacc[n][rg] = p;
                        rsum[rg] += p;
                    }
                for (int rg = 0; rg < 4; rg++) {
                    float v = rsum[rg];
                    for (int msk = 1; msk < 16; msk <<= 1) v += __shfl_xor(v, msk);
                    l_i[mt][rg] = l_i[mt][rg] * alpha[rg] + v;
                    for (int j = 0; j < 4; j++) acc[mt][j][rg] *= alpha[rg];
                }

                // P (C-layout) -> LDS (wave-private strip) -> A-layout
                const int prow0 = mt * 64 + wave * 16;
                for (int n = 0; n < 4; n++)
                    for (int rg = 0; rg < 4; rg++)
                        Ps[(prow0 + quad * 4 + rg) * 72 + n * 16 + ml] = f2bf(sacc[n][rg]);

                for (int kk = 0; kk < 2; kk++) {
                    bf16x8 pf = *(const bf16x8*)(Ps + (prow0 + ml) * 72 + kk * 32 + quad * 8);
                    for (int j = 0; j < 4; j++)
                        acc[mt][j] = __builtin_amdgcn_mfma_f32_16x16x32_bf16(pf, vf[j][kk], acc[mt][j], 0, 0, 0);
                }
            }

            if (pre) {
                const int nbuf = buf ^ 1;
                for (int pass = 0; pass < 2; pass++) {
                    int ki = pass * 32 + lr;
                    *(uint4*)(Ks[nbuf] + ki * 72 + lc8) = krg[pass];
                    unsigned short vs[8];
                    *(uint4*)vs = vrg[pass];
                    for (int jj = 0; jj < 8; jj++) {
                        int d = lc8 + jj;
                        Vs[nbuf][d * 72 + ((((ki >> 3) ^ (d >> 3)) & 7) << 3) + (ki & 7)] = vs[jj];
                    }
                }
            }
            __syncthreads();
        }

        // epilogue: ctx merged [B,S,D] bf16
        int b = bh >> 4, h = bh & 15;
        for (int mt = 0; mt < 2; mt++)
            for (int j = 0; j < 4; j++) {
                int d = j * 16 + ml;
                for (int rg = 0; rg < 4; rg++) {
                    int srow = q0 + mt * 64 + wave * 16 + quad * 4 + rg;
                    float val = acc[mt][j][rg] / l_i[mt][rg];
                    ctx[((size_t)(b * S_ + srow)) * D_ + h * 64 + d] = f2bf(val);
                }
            }
        __syncthreads();
    }
}

extern "C" void kernel_launch(void* const* d_in, const int* in_sizes, int n_in,
                              void* d_out, int out_size, void* d_ws, size_t ws_size,
                              hipStream_t stream) {
    const float* query = (const float*)d_in[0];
    const float* key_ = (const float*)d_in[1];
    const float* value = (const float*)d_in[2];
    // d_in[3] = mask: known causal, handled in-kernel
    const float* Wq = (const float*)d_in[4];
    const float* bq = (const float*)d_in[5];
    const float* Wk = (const float*)d_in[6];
    const float* bk = (const float*)d_in[7];
    const float* Wv = (const float*)d_in[8];
    const float* bv = (const float*)d_in[9];
    const float* Wo = (const float*)d_in[10];
    const float* bo = (const float*)d_in[11];
    float* out = (float*)d_out;

    const size_t XE = (size_t)M_ * D_;
    const size_t WE = (size_t)D_ * D_;
    char* ws = (char*)d_ws;
    unsigned short* xq = (unsigned short*)ws; ws += XE * 2;
    unsigned short* xk = (unsigned short*)ws; ws += XE * 2;
    unsigned short* xv = (unsigned short*)ws; ws += XE * 2;
    unsigned short* wqb = (unsigned short*)ws; ws += WE * 2;
    unsigned short* wkb = (unsigned short*)ws; ws += WE * 2;
    unsigned short* wvb = (unsigned short*)ws; ws += WE * 2;
    unsigned short* wob = (unsigned short*)ws; ws += WE * 2;
    unsigned short* qh = (unsigned short*)ws; ws += XE * 2;
    unsigned short* kh = (unsigned short*)ws; ws += XE * 2;
    unsigned short* vh = (unsigned short*)ws; ws += XE * 2;
    unsigned short* ctx = (unsigned short*)ws; ws += XE * 2;

    cvt_kernel<<<XE / 1024, 256, 0, stream>>>(query, xq, (int)XE);
    cvt_kernel<<<XE / 1024, 256, 0, stream>>>(key_, xk, (int)XE);
    cvt_kernel<<<XE / 1024, 256, 0, stream>>>(value, xv, (int)XE);
    cvt_kernel<<<WE / 1024, 256, 0, stream>>>(Wq, wqb, (int)WE);
    cvt_kernel<<<WE / 1024, 256, 0, stream>>>(Wk, wkb, (int)WE);
    cvt_kernel<<<WE / 1024, 256, 0, stream>>>(Wv, wvb, (int)WE);
    cvt_kernel<<<WE / 1024, 256, 0, stream>>>(Wo, wob, (int)WE);

    gemm_qkv<<<dim3(D_ / 128, M_ / 128, 3), 256, 0, stream>>>(
        xq, xk, xv, wqb, wkb, wvb, bq, bk, bv, qh, kh, vh);

    attn_kernel<<<dim3(8, B_ * H_), 256, 0, stream>>>(qh, kh, vh, ctx);

    gemm_out<<<dim3(D_ / 128, M_ / 128), 256, 0, stream>>>(ctx, wob, bo, out);
}

// Round 3
// 320.356 us; speedup vs baseline: 1.1992x; 1.1670x over previous
//
#include <hip/hip_runtime.h>

#define B_ 2
#define S_ 2048
#define D_ 1024
#define H_ 16
#define HD_ 64
#define M_ (B_ * S_)  // 4096

typedef __bf16 bf16x8 __attribute__((ext_vector_type(8)));
typedef float f32x4 __attribute__((ext_vector_type(4)));

__device__ inline unsigned short f2bf(float f) {
    unsigned int u = __builtin_bit_cast(unsigned int, f);
    u += 0x7fffu + ((u >> 16) & 1u);
    return (unsigned short)(u >> 16);
}

// async global->LDS, 16 bytes/lane; LDS dest = wave-uniform base + lane*16
__device__ inline void async_ld16(const unsigned short* g, unsigned short* l) {
    __builtin_amdgcn_global_load_lds(
        (const __attribute__((address_space(1))) unsigned int*)g,
        (__attribute__((address_space(3))) unsigned int*)l, 16, 0, 0);
}

// ---------------- f32 -> bf16 converts (fused launches) ----------------
__global__ __launch_bounds__(256) void cvt3(const float* __restrict__ a, const float* __restrict__ b,
                                            const float* __restrict__ c,
                                            unsigned short* __restrict__ oa, unsigned short* __restrict__ ob,
                                            unsigned short* __restrict__ oc) {
    const float* in = (blockIdx.y == 0) ? a : (blockIdx.y == 1) ? b : c;
    unsigned short* out = (blockIdx.y == 0) ? oa : (blockIdx.y == 1) ? ob : oc;
    int i = (blockIdx.x * 256 + threadIdx.x) * 4;
    float4 v = *(const float4*)(in + i);
    ushort4 o;
    o.x = f2bf(v.x); o.y = f2bf(v.y); o.z = f2bf(v.z); o.w = f2bf(v.w);
    *(ushort4*)(out + i) = o;
}

__global__ __launch_bounds__(256) void cvt4(const float* __restrict__ a, const float* __restrict__ b,
                                            const float* __restrict__ c, const float* __restrict__ d,
                                            unsigned short* __restrict__ oa, unsigned short* __restrict__ ob,
                                            unsigned short* __restrict__ oc, unsigned short* __restrict__ od) {
    int z = blockIdx.y;
    const float* in = (z == 0) ? a : (z == 1) ? b : (z == 2) ? c : d;
    unsigned short* out = (z == 0) ? oa : (z == 1) ? ob : (z == 2) ? oc : od;
    int i = (blockIdx.x * 256 + threadIdx.x) * 4;
    float4 v = *(const float4*)(in + i);
    ushort4 o;
    o.x = f2bf(v.x); o.y = f2bf(v.y); o.z = f2bf(v.z); o.w = f2bf(v.w);
    *(ushort4*)(out + i) = o;
}

// ---------------- GEMM core (m97 recipe): C[128x128] = A[M,K] @ W[N,K]^T ----------------
// global_load_lds staging into unpadded [128][64] LDS tiles with XOR chunk swizzle:
// LDS (row r, chunk p) holds global chunk p ^ (r&7).  (chunk = 8 bf16 = 16 B)
__device__ inline void gemm_compute(const unsigned short* __restrict__ A,
                                    const unsigned short* __restrict__ W,
                                    int K, int m0, int n0,
                                    unsigned short* As, unsigned short* Bs,
                                    f32x4 acc[4][4]) {
    const int t = threadIdx.x;
    const int lane = t & 63, wave = t >> 6;
    const int ml = lane & 15, quad = lane >> 4;
    const int wr = (wave >> 1) * 64, wc = (wave & 1) * 64;
    const int lrow = lane >> 3;             // 0..7
    const int gchunk = (lane & 7) ^ lrow;   // swizzled source chunk

    const f32x4 zero = {0.f, 0.f, 0.f, 0.f};
    for (int i = 0; i < 4; i++)
        for (int j = 0; j < 4; j++) acc[i][j] = zero;

    for (int kt = 0; kt < K; kt += 64) {
        // stage: wave covers rows wave*32 .. wave*32+31, 4 instrs x 8 rows, for A and B
        for (int i = 0; i < 4; i++) {
            int r = wave * 32 + i * 8;
            async_ld16(A + (size_t)(m0 + r + lrow) * K + kt + gchunk * 8, As + r * 64);
            async_ld16(W + (size_t)(n0 + r + lrow) * K + kt + gchunk * 8, Bs + r * 64);
        }
        __syncthreads();
        for (int kk = 0; kk < 2; ++kk) {
            const int co = ((kk * 4 + quad) ^ (ml & 7)) << 3;
            bf16x8 af[4], bfr[4];
            for (int i = 0; i < 4; i++)
                af[i] = *(const bf16x8*)(As + (wr + i * 16 + ml) * 64 + (((kk * 4 + quad) ^ (ml & 7)) << 3));
            for (int j = 0; j < 4; j++)
                bfr[j] = *(const bf16x8*)(Bs + (wc + j * 16 + ml) * 64 + (((kk * 4 + quad) ^ (ml & 7)) << 3));
            (void)co;
            for (int i = 0; i < 4; i++)
                for (int j = 0; j < 4; j++)
                    acc[i][j] = __builtin_amdgcn_mfma_f32_16x16x32_bf16(af[i], bfr[j], acc[i][j], 0, 0, 0);
        }
        __syncthreads();
    }
}

// ---------------- QKV projection (z selects q/k/v) ----------------
// q,k epilogue: head-split [B,H,S,64]; v epilogue: TRANSPOSED [B,H,64,S] (for attn V staging)
__global__ __launch_bounds__(256) void gemm_qkv(
    const unsigned short* __restrict__ xq, const unsigned short* __restrict__ xk,
    const unsigned short* __restrict__ xv,
    const unsigned short* __restrict__ wq, const unsigned short* __restrict__ wk,
    const unsigned short* __restrict__ wv,
    const float* __restrict__ bq, const float* __restrict__ bk, const float* __restrict__ bv,
    unsigned short* __restrict__ oq, unsigned short* __restrict__ ok,
    unsigned short* __restrict__ ov) {
    __shared__ unsigned short As[128 * 64], Bs[128 * 64];
    const unsigned short *A, *W;
    const float* bias;
    unsigned short* out;
    int z = blockIdx.z;
    if (z == 0) { A = xq; W = wq; bias = bq; out = oq; }
    else if (z == 1) { A = xk; W = wk; bias = bk; out = ok; }
    else { A = xv; W = wv; bias = bv; out = ov; }

    int m0 = blockIdx.y * 128, n0 = blockIdx.x * 128;
    f32x4 acc[4][4];
    gemm_compute(A, W, D_, m0, n0, As, Bs, acc);

    const int t = threadIdx.x, lane = t & 63, wave = t >> 6;
    const int ml = lane & 15, quad = lane >> 4;
    const int wr = (wave >> 1) * 64, wc = (wave & 1) * 64;
    if (z < 2) {
        for (int i = 0; i < 4; i++)
            for (int j = 0; j < 4; j++) {
                int n = n0 + wc + j * 16 + ml;
                float bb = bias[n];
                int h = n >> 6, d = n & 63;
                for (int rg = 0; rg < 4; rg++) {
                    int m = m0 + wr + i * 16 + quad * 4 + rg;
                    int b = m >> 11, s = m & 2047;
                    out[(((size_t)(b * H_ + h)) * S_ + s) * 64 + d] = f2bf(acc[i][j][rg] + bb);
                }
            }
    } else {
        // V^T: out[((b*H+h)*64 + d)*S + s], 4 consecutive s packed per store
        for (int i = 0; i < 4; i++)
            for (int j = 0; j < 4; j++) {
                int n = n0 + wc + j * 16 + ml;
                float bb = bias[n];
                int h = n >> 6, d = n & 63;
                int m = m0 + wr + i * 16 + quad * 4;
                int b = m >> 11, s = m & 2047;
                ushort4 pk;
                pk.x = f2bf(acc[i][j][0] + bb);
                pk.y = f2bf(acc[i][j][1] + bb);
                pk.z = f2bf(acc[i][j][2] + bb);
                pk.w = f2bf(acc[i][j][3] + bb);
                *(ushort4*)(out + ((size_t)(b * H_ + h) * 64 + d) * S_ + s) = pk;
            }
    }
}

// ---------------- output projection, f32 epilogue ----------------
__global__ __launch_bounds__(256) void gemm_out(const unsigned short* __restrict__ A,
                                                const unsigned short* __restrict__ W,
                                                const float* __restrict__ bias,
                                                float* __restrict__ out) {
    __shared__ unsigned short As[128 * 64], Bs[128 * 64];
    int m0 = blockIdx.y * 128, n0 = blockIdx.x * 128;
    f32x4 acc[4][4];
    gemm_compute(A, W, D_, m0, n0, As, Bs, acc);

    const int t = threadIdx.x, lane = t & 63, wave = t >> 6;
    const int ml = lane & 15, quad = lane >> 4;
    const int wr = (wave >> 1) * 64, wc = (wave & 1) * 64;
    for (int i = 0; i < 4; i++)
        for (int j = 0; j < 4; j++) {
            int n = n0 + wc + j * 16 + ml;
            float bb = bias[n];
            for (int rg = 0; rg < 4; rg++) {
                int m = m0 + wr + i * 16 + quad * 4 + rg;
                out[(size_t)m * D_ + n] = acc[i][j][rg] + bb;
            }
        }
}

// ---------------- flash attention, causal ----------------
// grid (32, B*H), LPT order (qb = 31 - blockIdx.x). 64 q-rows/block, wave w owns rows w*16..+15.
// K and V^T staged via global_load_lds into unpadded swizzled [64][64] LDS tiles.
__global__ __launch_bounds__(256, 4) void attn_kernel(const unsigned short* __restrict__ qh,
                                                      const unsigned short* __restrict__ kh,
                                                      const unsigned short* __restrict__ vt,
                                                      unsigned short* __restrict__ ctx) {
    __shared__ unsigned short Ks[64 * 64];
    __shared__ unsigned short Vs[64 * 64];
    __shared__ unsigned short Ps[64 * 72];

    const int qb = 31 - blockIdx.x;  // heavy blocks first (LPT)
    const int bh = blockIdx.y;
    const size_t base = (size_t)bh * S_ * 64;
    const int t = threadIdx.x, lane = t & 63, wave = t >> 6;
    const int ml = lane & 15, quad = lane >> 4;
    const int lrow = lane >> 3;            // 0..7
    const int gchunk = (lane & 7) ^ lrow;  // swizzled source chunk

    const int q0 = qb * 64;

    // persistent Q fragments (wave strip rows q0 + wave*16 + ml)
    bf16x8 qf[2];
    {
        int qrow = q0 + wave * 16 + ml;
        qf[0] = *(const bf16x8*)(qh + base + (size_t)qrow * 64 + quad * 8);
        qf[1] = *(const bf16x8*)(qh + base + (size_t)qrow * 64 + 32 + quad * 8);
    }

    const f32x4 zero = {0.f, 0.f, 0.f, 0.f};
    f32x4 acc[4];
    for (int j = 0; j < 4; j++) acc[j] = zero;
    float m_i[4], l_i[4];
    for (int rg = 0; rg < 4; rg++) { m_i[rg] = -INFINITY; l_i[rg] = 0.f; }

    const int nkt = qb + 1;
    for (int kt = 0; kt < nkt; kt++) {
        // stage K rows and V^T rows: 2 instrs each per wave (8 rows per instr)
        for (int i = 0; i < 2; i++) {
            int r = wave * 16 + i * 8;  // local row base (k-index for K, d for V^T)
            async_ld16(kh + base + (size_t)(kt * 64 + r + lrow) * 64 + gchunk * 8, Ks + r * 64);
            async_ld16(vt + base + (size_t)(r + lrow) * S_ + kt * 64 + gchunk * 8, Vs + r * 64);
        }
        __syncthreads();

        // S = Q K^T for this wave's 16 q-rows
        f32x4 sacc[4];
        for (int n = 0; n < 4; n++) sacc[n] = zero;
        for (int n = 0; n < 4; n++)
            for (int kk = 0; kk < 2; kk++) {
                bf16x8 kf = *(const bf16x8*)(Ks + (n * 16 + ml) * 64 + (((kk * 4 + quad) ^ (ml & 7)) << 3));
                sacc[n] = __builtin_amdgcn_mfma_f32_16x16x32_bf16(qf[kk], kf, sacc[n], 0, 0, 0);
            }

        const float scl = 0.125f;  // 1/sqrt(64)
        const bool diag = (kt == qb);
        for (int n = 0; n < 4; n++)
            for (int rg = 0; rg < 4; rg++) {
                float sv = sacc[n][rg] * scl;
                if (diag) {
                    int kidx = n * 16 + ml;
                    int qidx = wave * 16 + quad * 4 + rg;
                    if (kidx > qidx) sv = -3.0e38f;
                }
                sacc[n][rg] = sv;
            }

        // online softmax
        float alpha[4];
        for (int rg = 0; rg < 4; rg++) {
            float v = fmaxf(fmaxf(sacc[0][rg], sacc[1][rg]), fmaxf(sacc[2][rg], sacc[3][rg]));
            for (int msk = 1; msk < 16; msk <<= 1) v = fmaxf(v, __shfl_xor(v, msk));
            float mo = m_i[rg];
            float mc = fmaxf(mo, v);
            alpha[rg] = __expf(mo - mc);
            m_i[rg] = mc;
        }
        float rsum[4] = {0.f, 0.f, 0.f, 0.f};
        for (int n = 0; n < 4; n++)
            for (int rg = 0; rg < 4; rg++) {
                float p = __expf(sacc[n][rg] - m_i[rg]);
                sacc[n][rg] = p;
                rsum[rg] += p;
            }
        for (int rg = 0; rg < 4; rg++) {
            float v = rsum[rg];
            for (int msk = 1; msk < 16; msk <<= 1) v += __shfl_xor(v, msk);
            l_i[rg] = l_i[rg] * alpha[rg] + v;
            for (int j = 0; j < 4; j++) acc[j][rg] *= alpha[rg];
        }

        // P (C-layout) -> LDS (wave-private 16-row strip) -> A-layout fragments
        const int prow0 = wave * 16;
        for (int n = 0; n < 4; n++)
            for (int rg = 0; rg < 4; rg++)
                Ps[(prow0 + quad * 4 + rg) * 72 + n * 16 + ml] = f2bf(sacc[n][rg]);

        for (int kk = 0; kk < 2; kk++) {
            bf16x8 pf = *(const bf16x8*)(Ps + (prow0 + ml) * 72 + kk * 32 + quad * 8);
            for (int j = 0; j < 4; j++) {
                bf16x8 vf = *(const bf16x8*)(Vs + (j * 16 + ml) * 64 + (((kk * 4 + quad) ^ (ml & 7)) << 3));
                acc[j] = __builtin_amdgcn_mfma_f32_16x16x32_bf16(pf, vf, acc[j], 0, 0, 0);
            }
        }
        __syncthreads();
    }

    // epilogue: ctx merged [B,S,D] bf16
    int b = bh >> 4, h = bh & 15;
    for (int j = 0; j < 4; j++) {
        int d = j * 16 + ml;
        for (int rg = 0; rg < 4; rg++) {
            int srow = q0 + wave * 16 + quad * 4 + rg;
            float val = acc[j][rg] / l_i[rg];
            ctx[((size_t)(b * S_ + srow)) * D_ + h * 64 + d] = f2bf(val);
        }
    }
}

extern "C" void kernel_launch(void* const* d_in, const int* in_sizes, int n_in,
                              void* d_out, int out_size, void* d_ws, size_t ws_size,
                              hipStream_t stream) {
    const float* query = (const float*)d_in[0];
    const float* key_ = (const float*)d_in[1];
    const float* value = (const float*)d_in[2];
    // d_in[3] = mask: known causal, handled in-kernel
    const float* Wq = (const float*)d_in[4];
    const float* bq = (const float*)d_in[5];
    const float* Wk = (const float*)d_in[6];
    const float* bk = (const float*)d_in[7];
    const float* Wv = (const float*)d_in[8];
    const float* bv = (const float*)d_in[9];
    const float* Wo = (const float*)d_in[10];
    const float* bo = (const float*)d_in[11];
    float* out = (float*)d_out;

    const size_t XE = (size_t)M_ * D_;
    const size_t WE = (size_t)D_ * D_;
    char* ws = (char*)d_ws;
    unsigned short* xq = (unsigned short*)ws; ws += XE * 2;
    unsigned short* xk = (unsigned short*)ws; ws += XE * 2;
    unsigned short* xv = (unsigned short*)ws; ws += XE * 2;
    unsigned short* wqb = (unsigned short*)ws; ws += WE * 2;
    unsigned short* wkb = (unsigned short*)ws; ws += WE * 2;
    unsigned short* wvb = (unsigned short*)ws; ws += WE * 2;
    unsigned short* wob = (unsigned short*)ws; ws += WE * 2;
    unsigned short* qh = (unsigned short*)ws; ws += XE * 2;
    unsigned short* kh = (unsigned short*)ws; ws += XE * 2;
    unsigned short* vt = (unsigned short*)ws; ws += XE * 2;  // V transposed [B,H,64,S]
    unsigned short* ctx = (unsigned short*)ws; ws += XE * 2;

    cvt3<<<dim3(XE / 1024, 3), 256, 0, stream>>>(query, key_, value, xq, xk, xv);
    cvt4<<<dim3(WE / 1024, 4), 256, 0, stream>>>(Wq, Wk, Wv, Wo, wqb, wkb, wvb, wob);

    gemm_qkv<<<dim3(D_ / 128, M_ / 128, 3), 256, 0, stream>>>(
        xq, xk, xv, wqb, wkb, wvb, bq, bk, bv, qh, kh, vt);

    attn_kernel<<<dim3(32, B_ * H_), 256, 0, stream>>>(qh, kh, vt, ctx);

    gemm_out<<<dim3(D_ / 128, M_ / 128), 256, 0, stream>>>(ctx, wob, bo, out);
}

// Round 4
// 312.406 us; speedup vs baseline: 1.2297x; 1.0254x over previous
//
#include <hip/hip_runtime.h>

#define B_ 2
#define S_ 2048
#define D_ 1024
#define H_ 16
#define HD_ 64
#define M_ (B_ * S_)  // 4096

typedef __bf16 bf16x8 __attribute__((ext_vector_type(8)));
typedef float f32x4 __attribute__((ext_vector_type(4)));

__device__ inline unsigned short f2bf(float f) {
    unsigned int u = __builtin_bit_cast(unsigned int, f);
    u += 0x7fffu + ((u >> 16) & 1u);
    return (unsigned short)(u >> 16);
}

// async global->LDS, 16 bytes/lane
__device__ inline void async_ld16(const unsigned short* g, unsigned short* l) {
    __builtin_amdgcn_global_load_lds(
        (const __attribute__((address_space(1))) unsigned int*)g,
        (__attribute__((address_space(3))) unsigned int*)l, 16, 0, 0);
}

// DPP cross-lane reduction over 16 contiguous lanes (one DPP row)
template <int CTRL>
__device__ inline float dpp_mov(float v) {
    return __builtin_bit_cast(float,
        __builtin_amdgcn_update_dpp(0, __builtin_bit_cast(int, v), CTRL, 0xF, 0xF, true));
}
__device__ inline float row_max16(float v) {
    v = fmaxf(v, dpp_mov<0xB1>(v));   // quad_perm(1,0,3,2)
    v = fmaxf(v, dpp_mov<0x4E>(v));   // quad_perm(2,3,0,1)
    v = fmaxf(v, dpp_mov<0x141>(v));  // row_half_mirror
    v = fmaxf(v, dpp_mov<0x140>(v));  // row_mirror
    return v;
}
__device__ inline float row_sum16(float v) {
    v += dpp_mov<0xB1>(v);
    v += dpp_mov<0x4E>(v);
    v += dpp_mov<0x141>(v);
    v += dpp_mov<0x140>(v);
    return v;
}

// ---------------- f32 -> bf16 converts (fused launches) ----------------
__global__ __launch_bounds__(256) void cvt3(const float* __restrict__ a, const float* __restrict__ b,
                                            const float* __restrict__ c,
                                            unsigned short* __restrict__ oa, unsigned short* __restrict__ ob,
                                            unsigned short* __restrict__ oc) {
    const float* in = (blockIdx.y == 0) ? a : (blockIdx.y == 1) ? b : c;
    unsigned short* out = (blockIdx.y == 0) ? oa : (blockIdx.y == 1) ? ob : oc;
    int i = (blockIdx.x * 256 + threadIdx.x) * 4;
    float4 v = *(const float4*)(in + i);
    ushort4 o;
    o.x = f2bf(v.x); o.y = f2bf(v.y); o.z = f2bf(v.z); o.w = f2bf(v.w);
    *(ushort4*)(out + i) = o;
}

__global__ __launch_bounds__(256) void cvt4(const float* __restrict__ a, const float* __restrict__ b,
                                            const float* __restrict__ c, const float* __restrict__ d,
                                            unsigned short* __restrict__ oa, unsigned short* __restrict__ ob,
                                            unsigned short* __restrict__ oc, unsigned short* __restrict__ od) {
    int z = blockIdx.y;
    const float* in = (z == 0) ? a : (z == 1) ? b : (z == 2) ? c : d;
    unsigned short* out = (z == 0) ? oa : (z == 1) ? ob : (z == 2) ? oc : od;
    int i = (blockIdx.x * 256 + threadIdx.x) * 4;
    float4 v = *(const float4*)(in + i);
    ushort4 o;
    o.x = f2bf(v.x); o.y = f2bf(v.y); o.z = f2bf(v.z); o.w = f2bf(v.w);
    *(ushort4*)(out + i) = o;
}

// ---------------- GEMM core (m97 recipe): C[128x128] = A[M,K] @ W[N,K]^T ----------------
__device__ inline void gemm_compute(const unsigned short* __restrict__ A,
                                    const unsigned short* __restrict__ W,
                                    int K, int m0, int n0,
                                    unsigned short* As, unsigned short* Bs,
                                    f32x4 acc[4][4]) {
    const int t = threadIdx.x;
    const int lane = t & 63, wave = t >> 6;
    const int ml = lane & 15, quad = lane >> 4;
    const int wr = (wave >> 1) * 64, wc = (wave & 1) * 64;
    const int lrow = lane >> 3;
    const int gchunk = (lane & 7) ^ lrow;

    const f32x4 zero = {0.f, 0.f, 0.f, 0.f};
    for (int i = 0; i < 4; i++)
        for (int j = 0; j < 4; j++) acc[i][j] = zero;

    for (int kt = 0; kt < K; kt += 64) {
        for (int i = 0; i < 4; i++) {
            int r = wave * 32 + i * 8;
            async_ld16(A + (size_t)(m0 + r + lrow) * K + kt + gchunk * 8, As + r * 64);
            async_ld16(W + (size_t)(n0 + r + lrow) * K + kt + gchunk * 8, Bs + r * 64);
        }
        __syncthreads();
        for (int kk = 0; kk < 2; ++kk) {
            bf16x8 af[4], bfr[4];
            for (int i = 0; i < 4; i++)
                af[i] = *(const bf16x8*)(As + (wr + i * 16 + ml) * 64 + (((kk * 4 + quad) ^ (ml & 7)) << 3));
            for (int j = 0; j < 4; j++)
                bfr[j] = *(const bf16x8*)(Bs + (wc + j * 16 + ml) * 64 + (((kk * 4 + quad) ^ (ml & 7)) << 3));
            for (int i = 0; i < 4; i++)
                for (int j = 0; j < 4; j++)
                    acc[i][j] = __builtin_amdgcn_mfma_f32_16x16x32_bf16(af[i], bfr[j], acc[i][j], 0, 0, 0);
        }
        __syncthreads();
    }
}

// ---------------- QKV projection (z selects q/k/v) ----------------
__global__ __launch_bounds__(256) void gemm_qkv(
    const unsigned short* __restrict__ xq, const unsigned short* __restrict__ xk,
    const unsigned short* __restrict__ xv,
    const unsigned short* __restrict__ wq, const unsigned short* __restrict__ wk,
    const unsigned short* __restrict__ wv,
    const float* __restrict__ bq, const float* __restrict__ bk, const float* __restrict__ bv,
    unsigned short* __restrict__ oq, unsigned short* __restrict__ ok,
    unsigned short* __restrict__ ov) {
    __shared__ unsigned short As[128 * 64], Bs[128 * 64];
    const unsigned short *A, *W;
    const float* bias;
    unsigned short* out;
    int z = blockIdx.z;
    if (z == 0) { A = xq; W = wq; bias = bq; out = oq; }
    else if (z == 1) { A = xk; W = wk; bias = bk; out = ok; }
    else { A = xv; W = wv; bias = bv; out = ov; }

    int m0 = blockIdx.y * 128, n0 = blockIdx.x * 128;
    f32x4 acc[4][4];
    gemm_compute(A, W, D_, m0, n0, As, Bs, acc);

    const int t = threadIdx.x, lane = t & 63, wave = t >> 6;
    const int ml = lane & 15, quad = lane >> 4;
    const int wr = (wave >> 1) * 64, wc = (wave & 1) * 64;
    if (z < 2) {
        for (int i = 0; i < 4; i++)
            for (int j = 0; j < 4; j++) {
                int n = n0 + wc + j * 16 + ml;
                float bb = bias[n];
                int h = n >> 6, d = n & 63;
                for (int rg = 0; rg < 4; rg++) {
                    int m = m0 + wr + i * 16 + quad * 4 + rg;
                    int b = m >> 11, s = m & 2047;
                    out[(((size_t)(b * H_ + h)) * S_ + s) * 64 + d] = f2bf(acc[i][j][rg] + bb);
                }
            }
    } else {
        for (int i = 0; i < 4; i++)
            for (int j = 0; j < 4; j++) {
                int n = n0 + wc + j * 16 + ml;
                float bb = bias[n];
                int h = n >> 6, d = n & 63;
                int m = m0 + wr + i * 16 + quad * 4;
                int b = m >> 11, s = m & 2047;
                ushort4 pk;
                pk.x = f2bf(acc[i][j][0] + bb);
                pk.y = f2bf(acc[i][j][1] + bb);
                pk.z = f2bf(acc[i][j][2] + bb);
                pk.w = f2bf(acc[i][j][3] + bb);
                *(ushort4*)(out + ((size_t)(b * H_ + h) * 64 + d) * S_ + s) = pk;
            }
    }
}

// ---------------- output projection, f32 epilogue ----------------
__global__ __launch_bounds__(256) void gemm_out(const unsigned short* __restrict__ A,
                                                const unsigned short* __restrict__ W,
                                                const float* __restrict__ bias,
                                                float* __restrict__ out) {
    __shared__ unsigned short As[128 * 64], Bs[128 * 64];
    int m0 = blockIdx.y * 128, n0 = blockIdx.x * 128;
    f32x4 acc[4][4];
    gemm_compute(A, W, D_, m0, n0, As, Bs, acc);

    const int t = threadIdx.x, lane = t & 63, wave = t >> 6;
    const int ml = lane & 15, quad = lane >> 4;
    const int wr = (wave >> 1) * 64, wc = (wave & 1) * 64;
    for (int i = 0; i < 4; i++)
        for (int j = 0; j < 4; j++) {
            int n = n0 + wc + j * 16 + ml;
            float bb = bias[n];
            for (int rg = 0; rg < 4; rg++) {
                int m = m0 + wr + i * 16 + quad * 4 + rg;
                out[(size_t)m * D_ + n] = acc[i][j][rg] + bb;
            }
        }
}

// ---------------- flash attention, causal ----------------
// 1-D grid 1024, global LPT: qb = 31 - id/32, bh = id%32. 64 q-rows/block, 16/wave.
// 128-wide k-tiles, register-prefetch double-buffered staging, one barrier/tile.
__global__ __launch_bounds__(256, 2) void attn_kernel(const unsigned short* __restrict__ qh,
                                                      const unsigned short* __restrict__ kh,
                                                      const unsigned short* __restrict__ vt,
                                                      unsigned short* __restrict__ ctx) {
    __shared__ unsigned short Ks[2][128 * 64];  // [k][d], chunk-swizzled
    __shared__ unsigned short Vs[2][64 * 128];  // [d][k], chunk-swizzled
    __shared__ unsigned short Ps[64 * 128];     // P strips, chunk-swizzled

    const int qb = 31 - (blockIdx.x >> 5);
    const int bh = blockIdx.x & 31;
    const size_t base = (size_t)bh * S_ * 64;
    const int t = threadIdx.x, lane = t & 63, wave = t >> 6;
    const int ml = lane & 15, quad = lane >> 4;
    const int q0 = qb * 64;

    // persistent Q fragments
    bf16x8 qf[2];
    {
        int qrow = q0 + wave * 16 + ml;
        qf[0] = *(const bf16x8*)(qh + base + (size_t)qrow * 64 + quad * 8);
        qf[1] = *(const bf16x8*)(qh + base + (size_t)qrow * 64 + 32 + quad * 8);
    }

    const f32x4 zero = {0.f, 0.f, 0.f, 0.f};
    f32x4 acc[4];
    for (int j = 0; j < 4; j++) acc[j] = zero;
    float m_i[4], l_i[4];
    for (int rg = 0; rg < 4; rg++) { m_i[rg] = -INFINITY; l_i[rg] = 0.f; }

    const int ntiles = (qb + 2) >> 1;

    uint4 kreg[4], vreg[4];
    // preload tile 0
    for (int i = 0; i < 4; i++) {
        int idx = i * 256 + t;
        int r = idx >> 3, c = idx & 7;
        kreg[i] = *(const uint4*)(kh + base + (size_t)r * 64 + c * 8);
        int d = idx >> 4, c2 = idx & 15;
        vreg[i] = *(const uint4*)(vt + base + (size_t)d * S_ + c2 * 8);
    }

    for (int kt = 0; kt < ntiles; kt++) {
        const int buf = kt & 1;
        // commit prefetched regs to LDS
        for (int i = 0; i < 4; i++) {
            int idx = i * 256 + t;
            int r = idx >> 3, c = idx & 7;
            *(uint4*)(Ks[buf] + r * 64 + (((c ^ (r & 7)) & 7) << 3)) = kreg[i];
            int d = idx >> 4, c2 = idx & 15;
            *(uint4*)(Vs[buf] + d * 128 + (((c2 ^ (d & 15)) & 15) << 3)) = vreg[i];
        }
        __syncthreads();

        // prefetch next tile (latency hidden under compute below)
        if (kt + 1 < ntiles) {
            for (int i = 0; i < 4; i++) {
                int idx = i * 256 + t;
                int r = idx >> 3, c = idx & 7;
                kreg[i] = *(const uint4*)(kh + base + (size_t)((kt + 1) * 128 + r) * 64 + c * 8);
                int d = idx >> 4, c2 = idx & 15;
                vreg[i] = *(const uint4*)(vt + base + (size_t)d * S_ + (kt + 1) * 128 + c2 * 8);
            }
        }

        // S = Q K^T : 8 n-tiles x 2 kk
        f32x4 sacc[8];
        for (int n = 0; n < 8; n++) sacc[n] = zero;
        for (int n = 0; n < 8; n++)
            for (int kk = 0; kk < 2; kk++) {
                bf16x8 kf = *(const bf16x8*)(Ks[buf] + (n * 16 + ml) * 64 +
                                             (((kk * 4 + quad) ^ (ml & 7)) << 3));
                sacc[n] = __builtin_amdgcn_mfma_f32_16x16x32_bf16(qf[kk], kf, sacc[n], 0, 0, 0);
            }

        const float scl = 0.125f;  // 1/sqrt(64)
        const bool last = (kt == ntiles - 1);
        for (int n = 0; n < 8; n++)
            for (int rg = 0; rg < 4; rg++) {
                float sv = sacc[n][rg] * scl;
                if (last) {
                    int kidx = kt * 128 + n * 16 + ml;
                    int qidx = q0 + wave * 16 + quad * 4 + rg;
                    if (kidx > qidx) sv = -3.0e38f;
                }
                sacc[n][rg] = sv;
            }

        // online softmax (DPP reductions across the 16 ml lanes)
        float alpha[4];
        for (int rg = 0; rg < 4; rg++) {
            float v = sacc[0][rg];
            for (int n = 1; n < 8; n++) v = fmaxf(v, sacc[n][rg]);
            v = row_max16(v);
            float mo = m_i[rg];
            float mc = fmaxf(mo, v);
            alpha[rg] = __expf(mo - mc);
            m_i[rg] = mc;
        }
        float rsum[4] = {0.f, 0.f, 0.f, 0.f};
        for (int n = 0; n < 8; n++)
            for (int rg = 0; rg < 4; rg++) {
                float p = __expf(sacc[n][rg] - m_i[rg]);
                sacc[n][rg] = p;
                rsum[rg] += p;
            }
        for (int rg = 0; rg < 4; rg++) {
            float v = row_sum16(rsum[rg]);
            l_i[rg] = l_i[rg] * alpha[rg] + v;
            for (int j = 0; j < 4; j++) acc[j][rg] *= alpha[rg];
        }

        // P (C-layout) -> LDS strip -> A-layout fragments
        const int prow0 = wave * 16;
        for (int n = 0; n < 8; n++)
            for (int rg = 0; rg < 4; rg++) {
                int row = prow0 + quad * 4 + rg;
                int col = n * 16 + ml;
                int c = col >> 3;
                Ps[row * 128 + (((c ^ (row & 7)) & 15) << 3) + (col & 7)] = f2bf(sacc[n][rg]);
            }

        for (int kk = 0; kk < 4; kk++) {
            bf16x8 pf = *(const bf16x8*)(Ps + (prow0 + ml) * 128 +
                                         (((kk * 4 + quad) ^ (ml & 7)) << 3));
            for (int j = 0; j < 4; j++) {
                bf16x8 vf = *(const bf16x8*)(Vs[buf] + (j * 16 + ml) * 128 +
                                             (((kk * 4 + quad) ^ ml) << 3));
                acc[j] = __builtin_amdgcn_mfma_f32_16x16x32_bf16(pf, vf, acc[j], 0, 0, 0);
            }
        }
        // no trailing barrier: next iteration writes the other buffer,
        // and its pre-write barrier orders all waves' reads of this one.
    }

    // epilogue: ctx merged [B,S,D] bf16
    int b = bh >> 4, h = bh & 15;
    for (int j = 0; j < 4; j++) {
        int d = j * 16 + ml;
        for (int rg = 0; rg < 4; rg++) {
            int srow = q0 + wave * 16 + quad * 4 + rg;
            float val = acc[j][rg] / l_i[rg];
            ctx[((size_t)(b * S_ + srow)) * D_ + h * 64 + d] = f2bf(val);
        }
    }
}

extern "C" void kernel_launch(void* const* d_in, const int* in_sizes, int n_in,
                              void* d_out, int out_size, void* d_ws, size_t ws_size,
                              hipStream_t stream) {
    const float* query = (const float*)d_in[0];
    const float* key_ = (const float*)d_in[1];
    const float* value = (const float*)d_in[2];
    // d_in[3] = mask: known causal, handled in-kernel
    const float* Wq = (const float*)d_in[4];
    const float* bq = (const float*)d_in[5];
    const float* Wk = (const float*)d_in[6];
    const float* bk = (const float*)d_in[7];
    const float* Wv = (const float*)d_in[8];
    const float* bv = (const float*)d_in[9];
    const float* Wo = (const float*)d_in[10];
    const float* bo = (const float*)d_in[11];
    float* out = (float*)d_out;

    const size_t XE = (size_t)M_ * D_;
    const size_t WE = (size_t)D_ * D_;
    char* ws = (char*)d_ws;
    unsigned short* xq = (unsigned short*)ws; ws += XE * 2;
    unsigned short* xk = (unsigned short*)ws; ws += XE * 2;
    unsigned short* xv = (unsigned short*)ws; ws += XE * 2;
    unsigned short* wqb = (unsigned short*)ws; ws += WE * 2;
    unsigned short* wkb = (unsigned short*)ws; ws += WE * 2;
    unsigned short* wvb = (unsigned short*)ws; ws += WE * 2;
    unsigned short* wob = (unsigned short*)ws; ws += WE * 2;
    unsigned short* qh = (unsigned short*)ws; ws += XE * 2;
    unsigned short* kh = (unsigned short*)ws; ws += XE * 2;
    unsigned short* vt = (unsigned short*)ws; ws += XE * 2;  // V transposed [B,H,64,S]
    unsigned short* ctx = (unsigned short*)ws; ws += XE * 2;

    cvt3<<<dim3(XE / 1024, 3), 256, 0, stream>>>(query, key_, value, xq, xk, xv);
    cvt4<<<dim3(WE / 1024, 4), 256, 0, stream>>>(Wq, Wk, Wv, Wo, wqb, wkb, wvb, wob);

    gemm_qkv<<<dim3(D_ / 128, M_ / 128, 3), 256, 0, stream>>>(
        xq, xk, xv, wqb, wkb, wvb, bq, bk, bv, qh, kh, vt);

    attn_kernel<<<dim3(1024), 256, 0, stream>>>(qh, kh, vt, ctx);

    gemm_out<<<dim3(D_ / 128, M_ / 128), 256, 0, stream>>>(ctx, wob, bo, out);
}

// Round 5
// 261.545 us; speedup vs baseline: 1.4688x; 1.1945x over previous
//
#include <hip/hip_runtime.h>

#define B_ 2
#define S_ 2048
#define D_ 1024
#define H_ 16
#define HD_ 64
#define M_ (B_ * S_)  // 4096

typedef __bf16 bf16x8 __attribute__((ext_vector_type(8)));
typedef float f32x4 __attribute__((ext_vector_type(4)));

__device__ inline unsigned short f2bf(float f) {
    unsigned int u = __builtin_bit_cast(unsigned int, f);
    u += 0x7fffu + ((u >> 16) & 1u);
    return (unsigned short)(u >> 16);
}

// async global->LDS, 16 bytes/lane; LDS dest = wave-uniform base + lane*16
__device__ inline void async_ld16(const unsigned short* g, unsigned short* l) {
    __builtin_amdgcn_global_load_lds(
        (const __attribute__((address_space(1))) unsigned int*)g,
        (__attribute__((address_space(3))) unsigned int*)l, 16, 0, 0);
}

// DPP cross-lane reduction over 16 contiguous lanes (one DPP row)
template <int CTRL>
__device__ inline float dpp_mov(float v) {
    return __builtin_bit_cast(float,
        __builtin_amdgcn_update_dpp(0, __builtin_bit_cast(int, v), CTRL, 0xF, 0xF, true));
}
__device__ inline float row_max16(float v) {
    v = fmaxf(v, dpp_mov<0xB1>(v));   // quad_perm(1,0,3,2)
    v = fmaxf(v, dpp_mov<0x4E>(v));   // quad_perm(2,3,0,1)
    v = fmaxf(v, dpp_mov<0x141>(v));  // row_half_mirror
    v = fmaxf(v, dpp_mov<0x140>(v));  // row_mirror
    return v;
}
__device__ inline float row_sum16(float v) {
    v += dpp_mov<0xB1>(v);
    v += dpp_mov<0x4E>(v);
    v += dpp_mov<0x141>(v);
    v += dpp_mov<0x140>(v);
    return v;
}

// ---------------- f32 -> bf16 converts (fused launches) ----------------
__global__ __launch_bounds__(256) void cvt3(const float* __restrict__ a, const float* __restrict__ b,
                                            const float* __restrict__ c,
                                            unsigned short* __restrict__ oa, unsigned short* __restrict__ ob,
                                            unsigned short* __restrict__ oc) {
    const float* in = (blockIdx.y == 0) ? a : (blockIdx.y == 1) ? b : c;
    unsigned short* out = (blockIdx.y == 0) ? oa : (blockIdx.y == 1) ? ob : oc;
    int i = (blockIdx.x * 256 + threadIdx.x) * 4;
    float4 v = *(const float4*)(in + i);
    ushort4 o;
    o.x = f2bf(v.x); o.y = f2bf(v.y); o.z = f2bf(v.z); o.w = f2bf(v.w);
    *(ushort4*)(out + i) = o;
}

__global__ __launch_bounds__(256) void cvt4(const float* __restrict__ a, const float* __restrict__ b,
                                            const float* __restrict__ c, const float* __restrict__ d,
                                            unsigned short* __restrict__ oa, unsigned short* __restrict__ ob,
                                            unsigned short* __restrict__ oc, unsigned short* __restrict__ od) {
    int z = blockIdx.y;
    const float* in = (z == 0) ? a : (z == 1) ? b : (z == 2) ? c : d;
    unsigned short* out = (z == 0) ? oa : (z == 1) ? ob : (z == 2) ? oc : od;
    int i = (blockIdx.x * 256 + threadIdx.x) * 4;
    float4 v = *(const float4*)(in + i);
    ushort4 o;
    o.x = f2bf(v.x); o.y = f2bf(v.y); o.z = f2bf(v.z); o.w = f2bf(v.w);
    *(ushort4*)(out + i) = o;
}

// ---------------- GEMM core (m97 recipe): C[128x128] = A[M,K] @ W[N,K]^T ----------------
__device__ inline void gemm_compute(const unsigned short* __restrict__ A,
                                    const unsigned short* __restrict__ W,
                                    int K, int m0, int n0,
                                    unsigned short* As, unsigned short* Bs,
                                    f32x4 acc[4][4]) {
    const int t = threadIdx.x;
    const int lane = t & 63, wave = t >> 6;
    const int ml = lane & 15, quad = lane >> 4;
    const int wr = (wave >> 1) * 64, wc = (wave & 1) * 64;
    const int lrow = lane >> 3;
    const int gchunk = (lane & 7) ^ lrow;

    const f32x4 zero = {0.f, 0.f, 0.f, 0.f};
    for (int i = 0; i < 4; i++)
        for (int j = 0; j < 4; j++) acc[i][j] = zero;

    for (int kt = 0; kt < K; kt += 64) {
        for (int i = 0; i < 4; i++) {
            int r = wave * 32 + i * 8;
            async_ld16(A + (size_t)(m0 + r + lrow) * K + kt + gchunk * 8, As + r * 64);
            async_ld16(W + (size_t)(n0 + r + lrow) * K + kt + gchunk * 8, Bs + r * 64);
        }
        __syncthreads();
        for (int kk = 0; kk < 2; ++kk) {
            bf16x8 af[4], bfr[4];
            for (int i = 0; i < 4; i++)
                af[i] = *(const bf16x8*)(As + (wr + i * 16 + ml) * 64 + (((kk * 4 + quad) ^ (ml & 7)) << 3));
            for (int j = 0; j < 4; j++)
                bfr[j] = *(const bf16x8*)(Bs + (wc + j * 16 + ml) * 64 + (((kk * 4 + quad) ^ (ml & 7)) << 3));
            for (int i = 0; i < 4; i++)
                for (int j = 0; j < 4; j++)
                    acc[i][j] = __builtin_amdgcn_mfma_f32_16x16x32_bf16(af[i], bfr[j], acc[i][j], 0, 0, 0);
        }
        __syncthreads();
    }
}

// ---------------- QKV projection (z selects q/k/v) ----------------
__global__ __launch_bounds__(256) void gemm_qkv(
    const unsigned short* __restrict__ xq, const unsigned short* __restrict__ xk,
    const unsigned short* __restrict__ xv,
    const unsigned short* __restrict__ wq, const unsigned short* __restrict__ wk,
    const unsigned short* __restrict__ wv,
    const float* __restrict__ bq, const float* __restrict__ bk, const float* __restrict__ bv,
    unsigned short* __restrict__ oq, unsigned short* __restrict__ ok,
    unsigned short* __restrict__ ov) {
    __shared__ unsigned short As[128 * 64], Bs[128 * 64];
    const unsigned short *A, *W;
    const float* bias;
    unsigned short* out;
    int z = blockIdx.z;
    if (z == 0) { A = xq; W = wq; bias = bq; out = oq; }
    else if (z == 1) { A = xk; W = wk; bias = bk; out = ok; }
    else { A = xv; W = wv; bias = bv; out = ov; }

    int m0 = blockIdx.y * 128, n0 = blockIdx.x * 128;
    f32x4 acc[4][4];
    gemm_compute(A, W, D_, m0, n0, As, Bs, acc);

    const int t = threadIdx.x, lane = t & 63, wave = t >> 6;
    const int ml = lane & 15, quad = lane >> 4;
    const int wr = (wave >> 1) * 64, wc = (wave & 1) * 64;
    if (z < 2) {
        for (int i = 0; i < 4; i++)
            for (int j = 0; j < 4; j++) {
                int n = n0 + wc + j * 16 + ml;
                float bb = bias[n];
                int h = n >> 6, d = n & 63;
                for (int rg = 0; rg < 4; rg++) {
                    int m = m0 + wr + i * 16 + quad * 4 + rg;
                    int b = m >> 11, s = m & 2047;
                    out[(((size_t)(b * H_ + h)) * S_ + s) * 64 + d] = f2bf(acc[i][j][rg] + bb);
                }
            }
    } else {
        for (int i = 0; i < 4; i++)
            for (int j = 0; j < 4; j++) {
                int n = n0 + wc + j * 16 + ml;
                float bb = bias[n];
                int h = n >> 6, d = n & 63;
                int m = m0 + wr + i * 16 + quad * 4;
                int b = m >> 11, s = m & 2047;
                ushort4 pk;
                pk.x = f2bf(acc[i][j][0] + bb);
                pk.y = f2bf(acc[i][j][1] + bb);
                pk.z = f2bf(acc[i][j][2] + bb);
                pk.w = f2bf(acc[i][j][3] + bb);
                *(ushort4*)(out + ((size_t)(b * H_ + h) * 64 + d) * S_ + s) = pk;
            }
    }
}

// ---------------- output projection, f32 epilogue ----------------
__global__ __launch_bounds__(256) void gemm_out(const unsigned short* __restrict__ A,
                                                const unsigned short* __restrict__ W,
                                                const float* __restrict__ bias,
                                                float* __restrict__ out) {
    __shared__ unsigned short As[128 * 64], Bs[128 * 64];
    int m0 = blockIdx.y * 128, n0 = blockIdx.x * 128;
    f32x4 acc[4][4];
    gemm_compute(A, W, D_, m0, n0, As, Bs, acc);

    const int t = threadIdx.x, lane = t & 63, wave = t >> 6;
    const int ml = lane & 15, quad = lane >> 4;
    const int wr = (wave >> 1) * 64, wc = (wave & 1) * 64;
    for (int i = 0; i < 4; i++)
        for (int j = 0; j < 4; j++) {
            int n = n0 + wc + j * 16 + ml;
            float bb = bias[n];
            for (int rg = 0; rg < 4; rg++) {
                int m = m0 + wr + i * 16 + quad * 4 + rg;
                out[(size_t)m * D_ + n] = acc[i][j][rg] + bb;
            }
        }
}

// ---------------- flash attention, causal ----------------
// 1-D grid 1024, global LPT: qb = 31 - id/32, bh = id%32. 64 q-rows/block, 16/wave.
// 128-wide k-tiles; global_load_lds DOUBLE-BUFFERED staging (no VGPR prefetch,
// no scratch): issue tile kt+1 into buf^1, compute tile kt, barrier (vmcnt drain
// = next tile ready; also orders buffer reuse). One barrier per tile.
__global__ __launch_bounds__(256, 2) void attn_kernel(const unsigned short* __restrict__ qh,
                                                      const unsigned short* __restrict__ kh,
                                                      const unsigned short* __restrict__ vt,
                                                      unsigned short* __restrict__ ctx) {
    __shared__ unsigned short Ks[2][128 * 64];  // [k][d], chunk-swizzled (^row&7)
    __shared__ unsigned short Vs[2][64 * 128];  // [d][k], chunk-swizzled (^d&15)
    __shared__ unsigned short Ps[64 * 128];     // P strips, chunk-swizzled

    const int qb = 31 - (blockIdx.x >> 5);
    const int bh = blockIdx.x & 31;
    const size_t base = (size_t)bh * S_ * 64;
    const int t = threadIdx.x, lane = t & 63, wave = t >> 6;
    const int ml = lane & 15, quad = lane >> 4;
    const int lrow = lane >> 3;            // 0..7 (K staging row-in-group)
    const int gchunk = (lane & 7) ^ lrow;  // K swizzled source chunk
    const int vrow = lane >> 4;            // 0..3 (V staging row-in-group)
    const int q0 = qb * 64;

    // persistent Q fragments
    bf16x8 qf[2];
    {
        int qrow = q0 + wave * 16 + ml;
        qf[0] = *(const bf16x8*)(qh + base + (size_t)qrow * 64 + quad * 8);
        qf[1] = *(const bf16x8*)(qh + base + (size_t)qrow * 64 + 32 + quad * 8);
    }

    const f32x4 zero = {0.f, 0.f, 0.f, 0.f};
    f32x4 acc[4];
    for (int j = 0; j < 4; j++) acc[j] = zero;
    float m_i[4], l_i[4];
    for (int rg = 0; rg < 4; rg++) { m_i[rg] = -INFINITY; l_i[rg] = 0.f; }

    const int ntiles = (qb + 2) >> 1;

    // issue K/V tile kt into LDS buffer bb (8 async instrs per wave)
    auto issue_tile = [&](int kt, int bb) {
        for (int i = 0; i < 4; i++) {
            int r = wave * 32 + i * 8;  // K rows r..r+7
            async_ld16(kh + base + (size_t)(kt * 128 + r + lrow) * 64 + gchunk * 8,
                       Ks[bb] + r * 64);
            int dd = wave * 16 + i * 4;  // V rows dd..dd+3
            int d = dd + vrow;
            async_ld16(vt + base + (size_t)d * S_ + kt * 128 + (((lane & 15) ^ (d & 15)) << 3),
                       Vs[bb] + dd * 128);
        }
    };

    issue_tile(0, 0);
    __syncthreads();  // vmcnt(0) drain -> tile 0 resident

    for (int kt = 0; kt < ntiles; kt++) {
        const int buf = kt & 1;
        if (kt + 1 < ntiles) issue_tile(kt + 1, buf ^ 1);

        // S = Q K^T : 8 n-tiles x 2 kk
        f32x4 sacc[8];
        for (int n = 0; n < 8; n++) sacc[n] = zero;
        for (int n = 0; n < 8; n++)
            for (int kk = 0; kk < 2; kk++) {
                bf16x8 kf = *(const bf16x8*)(Ks[buf] + (n * 16 + ml) * 64 +
                                             (((kk * 4 + quad) ^ (ml & 7)) << 3));
                sacc[n] = __builtin_amdgcn_mfma_f32_16x16x32_bf16(qf[kk], kf, sacc[n], 0, 0, 0);
            }

        const float scl = 0.125f;  // 1/sqrt(64)
        const bool last = (kt == ntiles - 1);
        for (int n = 0; n < 8; n++)
            for (int rg = 0; rg < 4; rg++) {
                float sv = sacc[n][rg] * scl;
                if (last) {
                    int kidx = kt * 128 + n * 16 + ml;
                    int qidx = q0 + wave * 16 + quad * 4 + rg;
                    if (kidx > qidx) sv = -3.0e38f;
                }
                sacc[n][rg] = sv;
            }

        // online softmax (DPP reductions across the 16 ml lanes)
        float alpha[4];
        for (int rg = 0; rg < 4; rg++) {
            float v = sacc[0][rg];
            for (int n = 1; n < 8; n++) v = fmaxf(v, sacc[n][rg]);
            v = row_max16(v);
            float mo = m_i[rg];
            float mc = fmaxf(mo, v);
            alpha[rg] = __expf(mo - mc);
            m_i[rg] = mc;
        }
        float rsum[4] = {0.f, 0.f, 0.f, 0.f};
        for (int n = 0; n < 8; n++)
            for (int rg = 0; rg < 4; rg++) {
                float p = __expf(sacc[n][rg] - m_i[rg]);
                sacc[n][rg] = p;
                rsum[rg] += p;
            }
        for (int rg = 0; rg < 4; rg++) {
            float v = row_sum16(rsum[rg]);
            l_i[rg] = l_i[rg] * alpha[rg] + v;
            for (int j = 0; j < 4; j++) acc[j][rg] *= alpha[rg];
        }

        // P (C-layout) -> LDS strip (wave-private) -> A-layout fragments
        const int prow0 = wave * 16;
        for (int n = 0; n < 8; n++)
            for (int rg = 0; rg < 4; rg++) {
                int row = prow0 + quad * 4 + rg;
                int col = n * 16 + ml;
                int c = col >> 3;
                Ps[row * 128 + (((c ^ (row & 7)) & 15) << 3) + (col & 7)] = f2bf(sacc[n][rg]);
            }

        for (int kk = 0; kk < 4; kk++) {
            bf16x8 pf = *(const bf16x8*)(Ps + (prow0 + ml) * 128 +
                                         (((kk * 4 + quad) ^ (ml & 7)) << 3));
            for (int j = 0; j < 4; j++) {
                bf16x8 vf = *(const bf16x8*)(Vs[buf] + (j * 16 + ml) * 128 +
                                             (((kk * 4 + quad) ^ ml) << 3));
                acc[j] = __builtin_amdgcn_mfma_f32_16x16x32_bf16(pf, vf, acc[j], 0, 0, 0);
            }
        }

        __syncthreads();  // drains next tile's loads; orders buffer reuse
    }

    // epilogue: ctx merged [B,S,D] bf16
    int b = bh >> 4, h = bh & 15;
    for (int j = 0; j < 4; j++) {
        int d = j * 16 + ml;
        for (int rg = 0; rg < 4; rg++) {
            int srow = q0 + wave * 16 + quad * 4 + rg;
            float val = acc[j][rg] / l_i[rg];
            ctx[((size_t)(b * S_ + srow)) * D_ + h * 64 + d] = f2bf(val);
        }
    }
}

extern "C" void kernel_launch(void* const* d_in, const int* in_sizes, int n_in,
                              void* d_out, int out_size, void* d_ws, size_t ws_size,
                              hipStream_t stream) {
    const float* query = (const float*)d_in[0];
    const float* key_ = (const float*)d_in[1];
    const float* value = (const float*)d_in[2];
    // d_in[3] = mask: known causal, handled in-kernel
    const float* Wq = (const float*)d_in[4];
    const float* bq = (const float*)d_in[5];
    const float* Wk = (const float*)d_in[6];
    const float* bk = (const float*)d_in[7];
    const float* Wv = (const float*)d_in[8];
    const float* bv = (const float*)d_in[9];
    const float* Wo = (const float*)d_in[10];
    const float* bo = (const float*)d_in[11];
    float* out = (float*)d_out;

    const size_t XE = (size_t)M_ * D_;
    const size_t WE = (size_t)D_ * D_;
    char* ws = (char*)d_ws;
    unsigned short* xq = (unsigned short*)ws; ws += XE * 2;
    unsigned short* xk = (unsigned short*)ws; ws += XE * 2;
    unsigned short* xv = (unsigned short*)ws; ws += XE * 2;
    unsigned short* wqb = (unsigned short*)ws; ws += WE * 2;
    unsigned short* wkb = (unsigned short*)ws; ws += WE * 2;
    unsigned short* wvb = (unsigned short*)ws; ws += WE * 2;
    unsigned short* wob = (unsigned short*)ws; ws += WE * 2;
    unsigned short* qh = (unsigned short*)ws; ws += XE * 2;
    unsigned short* kh = (unsigned short*)ws; ws += XE * 2;
    unsigned short* vt = (unsigned short*)ws; ws += XE * 2;  // V transposed [B,H,64,S]
    unsigned short* ctx = (unsigned short*)ws; ws += XE * 2;

    cvt3<<<dim3(XE / 1024, 3), 256, 0, stream>>>(query, key_, value, xq, xk, xv);
    cvt4<<<dim3(WE / 1024, 4), 256, 0, stream>>>(Wq, Wk, Wv, Wo, wqb, wkb, wvb, wob);

    gemm_qkv<<<dim3(D_ / 128, M_ / 128, 3), 256, 0, stream>>>(
        xq, xk, xv, wqb, wkb, wvb, bq, bk, bv, qh, kh, vt);

    attn_kernel<<<dim3(1024), 256, 0, stream>>>(qh, kh, vt, ctx);

    gemm_out<<<dim3(D_ / 128, M_ / 128), 256, 0, stream>>>(ctx, wob, bo, out);
}

// Round 6
// 256.696 us; speedup vs baseline: 1.4966x; 1.0189x over previous
//
#include <hip/hip_runtime.h>

#define B_ 2
#define S_ 2048
#define D_ 1024
#define H_ 16
#define HD_ 64
#define M_ (B_ * S_)  // 4096

typedef __bf16 bf16x8 __attribute__((ext_vector_type(8)));
typedef float f32x4 __attribute__((ext_vector_type(4)));

__device__ inline unsigned short f2bf(float f) {
    unsigned int u = __builtin_bit_cast(unsigned int, f);
    u += 0x7fffu + ((u >> 16) & 1u);
    return (unsigned short)(u >> 16);
}

// async global->LDS, 16 bytes/lane; LDS dest = wave-uniform base + lane*16
__device__ inline void async_ld16(const unsigned short* g, unsigned short* l) {
    __builtin_amdgcn_global_load_lds(
        (const __attribute__((address_space(1))) unsigned int*)g,
        (__attribute__((address_space(3))) unsigned int*)l, 16, 0, 0);
}

// DPP cross-lane reduction over 16 contiguous lanes (one DPP row)
template <int CTRL>
__device__ inline float dpp_mov(float v) {
    return __builtin_bit_cast(float,
        __builtin_amdgcn_update_dpp(0, __builtin_bit_cast(int, v), CTRL, 0xF, 0xF, true));
}
__device__ inline float row_max16(float v) {
    v = fmaxf(v, dpp_mov<0xB1>(v));   // quad_perm(1,0,3,2)
    v = fmaxf(v, dpp_mov<0x4E>(v));   // quad_perm(2,3,0,1)
    v = fmaxf(v, dpp_mov<0x141>(v));  // row_half_mirror
    v = fmaxf(v, dpp_mov<0x140>(v));  // row_mirror
    return v;
}
__device__ inline float row_sum16(float v) {
    v += dpp_mov<0xB1>(v);
    v += dpp_mov<0x4E>(v);
    v += dpp_mov<0x141>(v);
    v += dpp_mov<0x140>(v);
    return v;
}

// ---------------- f32 -> bf16 convert: all 7 tensors in one launch ----------------
__global__ __launch_bounds__(256) void cvt_all(
    const float* __restrict__ i0, const float* __restrict__ i1, const float* __restrict__ i2,
    const float* __restrict__ i3, const float* __restrict__ i4, const float* __restrict__ i5,
    const float* __restrict__ i6,
    unsigned short* __restrict__ o0, unsigned short* __restrict__ o1, unsigned short* __restrict__ o2,
    unsigned short* __restrict__ o3, unsigned short* __restrict__ o4, unsigned short* __restrict__ o5,
    unsigned short* __restrict__ o6, int nbig, int nsmall) {
    int z = blockIdx.y;
    const float* in = (z == 0) ? i0 : (z == 1) ? i1 : (z == 2) ? i2 : (z == 3) ? i3
                     : (z == 4) ? i4 : (z == 5) ? i5 : i6;
    unsigned short* out = (z == 0) ? o0 : (z == 1) ? o1 : (z == 2) ? o2 : (z == 3) ? o3
                         : (z == 4) ? o4 : (z == 5) ? o5 : o6;
    int n = (z < 3) ? nbig : nsmall;
    int i = (blockIdx.x * 256 + threadIdx.x) * 4;
    if (i >= n) return;
    float4 v = *(const float4*)(in + i);
    ushort4 o;
    o.x = f2bf(v.x); o.y = f2bf(v.y); o.z = f2bf(v.z); o.w = f2bf(v.w);
    *(ushort4*)(out + i) = o;
}

// ---------------- GEMM core, double-buffered: C[128x128] = A[M,K] @ W[N,K]^T ----------------
// global_load_lds staging into unpadded [128][64] LDS tiles with XOR chunk swizzle.
// Tile kt+1 issued at top of iteration kt; one barrier per iteration (its vmcnt(0)
// drain lands after a full compute phase -> latency mostly hidden).
__device__ inline void gemm_compute(const unsigned short* __restrict__ A,
                                    const unsigned short* __restrict__ W,
                                    int K, int m0, int n0,
                                    unsigned short* As0, unsigned short* As1,
                                    unsigned short* Bs0, unsigned short* Bs1,
                                    f32x4 acc[4][4]) {
    const int t = threadIdx.x;
    const int lane = t & 63, wave = t >> 6;
    const int ml = lane & 15, quad = lane >> 4;
    const int wr = (wave >> 1) * 64, wc = (wave & 1) * 64;
    const int lrow = lane >> 3;
    const int gchunk = (lane & 7) ^ lrow;

    const f32x4 zero = {0.f, 0.f, 0.f, 0.f};
    for (int i = 0; i < 4; i++)
        for (int j = 0; j < 4; j++) acc[i][j] = zero;

    const int niter = K >> 6;

    auto issue = [&](int kt, unsigned short* As, unsigned short* Bs) {
        int k0 = kt << 6;
        for (int i = 0; i < 4; i++) {
            int r = wave * 32 + i * 8;
            async_ld16(A + (size_t)(m0 + r + lrow) * K + k0 + gchunk * 8, As + r * 64);
            async_ld16(W + (size_t)(n0 + r + lrow) * K + k0 + gchunk * 8, Bs + r * 64);
        }
    };

    issue(0, As0, Bs0);
    __syncthreads();

    for (int kt = 0; kt < niter; kt++) {
        unsigned short* As = (kt & 1) ? As1 : As0;
        unsigned short* Bs = (kt & 1) ? Bs1 : Bs0;
        if (kt + 1 < niter) issue(kt + 1, (kt & 1) ? As0 : As1, (kt & 1) ? Bs0 : Bs1);

        for (int kk = 0; kk < 2; ++kk) {
            bf16x8 af[4], bfr[4];
            for (int i = 0; i < 4; i++)
                af[i] = *(const bf16x8*)(As + (wr + i * 16 + ml) * 64 + (((kk * 4 + quad) ^ (ml & 7)) << 3));
            for (int j = 0; j < 4; j++)
                bfr[j] = *(const bf16x8*)(Bs + (wc + j * 16 + ml) * 64 + (((kk * 4 + quad) ^ (ml & 7)) << 3));
            for (int i = 0; i < 4; i++)
                for (int j = 0; j < 4; j++)
                    acc[i][j] = __builtin_amdgcn_mfma_f32_16x16x32_bf16(af[i], bfr[j], acc[i][j], 0, 0, 0);
        }
        __syncthreads();  // drains next tile's loads; orders buffer reuse
    }
}

// ---------------- QKV projection (z selects q/k/v) ----------------
__global__ __launch_bounds__(256) void gemm_qkv(
    const unsigned short* __restrict__ xq, const unsigned short* __restrict__ xk,
    const unsigned short* __restrict__ xv,
    const unsigned short* __restrict__ wq, const unsigned short* __restrict__ wk,
    const unsigned short* __restrict__ wv,
    const float* __restrict__ bq, const float* __restrict__ bk, const float* __restrict__ bv,
    unsigned short* __restrict__ oq, unsigned short* __restrict__ ok,
    unsigned short* __restrict__ ov) {
    __shared__ unsigned short As0[128 * 64], As1[128 * 64], Bs0[128 * 64], Bs1[128 * 64];
    const unsigned short *A, *W;
    const float* bias;
    unsigned short* out;
    int z = blockIdx.z;
    if (z == 0) { A = xq; W = wq; bias = bq; out = oq; }
    else if (z == 1) { A = xk; W = wk; bias = bk; out = ok; }
    else { A = xv; W = wv; bias = bv; out = ov; }

    int m0 = blockIdx.y * 128, n0 = blockIdx.x * 128;
    f32x4 acc[4][4];
    gemm_compute(A, W, D_, m0, n0, As0, As1, Bs0, Bs1, acc);

    const int t = threadIdx.x, lane = t & 63, wave = t >> 6;
    const int ml = lane & 15, quad = lane >> 4;
    const int wr = (wave >> 1) * 64, wc = (wave & 1) * 64;
    if (z < 2) {
        for (int i = 0; i < 4; i++)
            for (int j = 0; j < 4; j++) {
                int n = n0 + wc + j * 16 + ml;
                float bb = bias[n];
                int h = n >> 6, d = n & 63;
                for (int rg = 0; rg < 4; rg++) {
                    int m = m0 + wr + i * 16 + quad * 4 + rg;
                    int b = m >> 11, s = m & 2047;
                    out[(((size_t)(b * H_ + h)) * S_ + s) * 64 + d] = f2bf(acc[i][j][rg] + bb);
                }
            }
    } else {
        for (int i = 0; i < 4; i++)
            for (int j = 0; j < 4; j++) {
                int n = n0 + wc + j * 16 + ml;
                float bb = bias[n];
                int h = n >> 6, d = n & 63;
                int m = m0 + wr + i * 16 + quad * 4;
                int b = m >> 11, s = m & 2047;
                ushort4 pk;
                pk.x = f2bf(acc[i][j][0] + bb);
                pk.y = f2bf(acc[i][j][1] + bb);
                pk.z = f2bf(acc[i][j][2] + bb);
                pk.w = f2bf(acc[i][j][3] + bb);
                *(ushort4*)(out + ((size_t)(b * H_ + h) * 64 + d) * S_ + s) = pk;
            }
    }
}

// ---------------- output projection, f32 epilogue ----------------
__global__ __launch_bounds__(256) void gemm_out(const unsigned short* __restrict__ A,
                                                const unsigned short* __restrict__ W,
                                                const float* __restrict__ bias,
                                                float* __restrict__ out) {
    __shared__ unsigned short As0[128 * 64], As1[128 * 64], Bs0[128 * 64], Bs1[128 * 64];
    int m0 = blockIdx.y * 128, n0 = blockIdx.x * 128;
    f32x4 acc[4][4];
    gemm_compute(A, W, D_, m0, n0, As0, As1, Bs0, Bs1, acc);

    const int t = threadIdx.x, lane = t & 63, wave = t >> 6;
    const int ml = lane & 15, quad = lane >> 4;
    const int wr = (wave >> 1) * 64, wc = (wave & 1) * 64;
    for (int i = 0; i < 4; i++)
        for (int j = 0; j < 4; j++) {
            int n = n0 + wc + j * 16 + ml;
            float bb = bias[n];
            for (int rg = 0; rg < 4; rg++) {
                int m = m0 + wr + i * 16 + quad * 4 + rg;
                out[(size_t)m * D_ + n] = acc[i][j][rg] + bb;
            }
        }
}

// ---------------- flash attention, causal ----------------
// 1-D grid 1024, global LPT: qb = 31 - id/32, bh = id%32. 64 q-rows/block, 16/wave.
// 128-wide k-tiles; global_load_lds double-buffered staging, one barrier/tile.
__global__ __launch_bounds__(256, 2) void attn_kernel(const unsigned short* __restrict__ qh,
                                                      const unsigned short* __restrict__ kh,
                                                      const unsigned short* __restrict__ vt,
                                                      unsigned short* __restrict__ ctx) {
    __shared__ unsigned short Ks[2][128 * 64];  // [k][d], chunk-swizzled (^row&7)
    __shared__ unsigned short Vs[2][64 * 128];  // [d][k], chunk-swizzled (^d&15)
    __shared__ unsigned short Ps[64 * 128];     // P strips, chunk-swizzled

    const int qb = 31 - (blockIdx.x >> 5);
    const int bh = blockIdx.x & 31;
    const size_t base = (size_t)bh * S_ * 64;
    const int t = threadIdx.x, lane = t & 63, wave = t >> 6;
    const int ml = lane & 15, quad = lane >> 4;
    const int lrow = lane >> 3;            // 0..7 (K staging row-in-group)
    const int gchunk = (lane & 7) ^ lrow;  // K swizzled source chunk
    const int vrow = lane >> 4;            // 0..3 (V staging row-in-group)
    const int q0 = qb * 64;

    // persistent Q fragments
    bf16x8 qf[2];
    {
        int qrow = q0 + wave * 16 + ml;
        qf[0] = *(const bf16x8*)(qh + base + (size_t)qrow * 64 + quad * 8);
        qf[1] = *(const bf16x8*)(qh + base + (size_t)qrow * 64 + 32 + quad * 8);
    }

    const f32x4 zero = {0.f, 0.f, 0.f, 0.f};
    f32x4 acc[4];
    for (int j = 0; j < 4; j++) acc[j] = zero;
    float m_i[4], l_i[4];
    for (int rg = 0; rg < 4; rg++) { m_i[rg] = -INFINITY; l_i[rg] = 0.f; }

    const int ntiles = (qb + 2) >> 1;

    // issue K/V tile kt into LDS buffer bb (8 async instrs per wave)
    auto issue_tile = [&](int kt, int bb) {
        for (int i = 0; i < 4; i++) {
            int r = wave * 32 + i * 8;  // K rows r..r+7
            async_ld16(kh + base + (size_t)(kt * 128 + r + lrow) * 64 + gchunk * 8,
                       Ks[bb] + r * 64);
            int dd = wave * 16 + i * 4;  // V rows dd..dd+3
            int d = dd + vrow;
            async_ld16(vt + base + (size_t)d * S_ + kt * 128 + (((lane & 15) ^ (d & 15)) << 3),
                       Vs[bb] + dd * 128);
        }
    };

    issue_tile(0, 0);
    __syncthreads();  // vmcnt(0) drain -> tile 0 resident

    for (int kt = 0; kt < ntiles; kt++) {
        const int buf = kt & 1;
        if (kt + 1 < ntiles) issue_tile(kt + 1, buf ^ 1);

        // S = Q K^T : 8 n-tiles x 2 kk
        f32x4 sacc[8];
        for (int n = 0; n < 8; n++) sacc[n] = zero;
        for (int n = 0; n < 8; n++)
            for (int kk = 0; kk < 2; kk++) {
                bf16x8 kf = *(const bf16x8*)(Ks[buf] + (n * 16 + ml) * 64 +
                                             (((kk * 4 + quad) ^ (ml & 7)) << 3));
                sacc[n] = __builtin_amdgcn_mfma_f32_16x16x32_bf16(qf[kk], kf, sacc[n], 0, 0, 0);
            }

        const float scl = 0.125f;  // 1/sqrt(64)
        const bool last = (kt == ntiles - 1);
        for (int n = 0; n < 8; n++)
            for (int rg = 0; rg < 4; rg++) {
                float sv = sacc[n][rg] * scl;
                if (last) {
                    int kidx = kt * 128 + n * 16 + ml;
                    int qidx = q0 + wave * 16 + quad * 4 + rg;
                    if (kidx > qidx) sv = -3.0e38f;
                }
                sacc[n][rg] = sv;
            }

        // online softmax (DPP reductions across the 16 ml lanes)
        float alpha[4];
        for (int rg = 0; rg < 4; rg++) {
            float v = sacc[0][rg];
            for (int n = 1; n < 8; n++) v = fmaxf(v, sacc[n][rg]);
            v = row_max16(v);
            float mo = m_i[rg];
            float mc = fmaxf(mo, v);
            alpha[rg] = __expf(mo - mc);
            m_i[rg] = mc;
        }
        float rsum[4] = {0.f, 0.f, 0.f, 0.f};
        for (int n = 0; n < 8; n++)
            for (int rg = 0; rg < 4; rg++) {
                float p = __expf(sacc[n][rg] - m_i[rg]);
                sacc[n][rg] = p;
                rsum[rg] += p;
            }
        for (int rg = 0; rg < 4; rg++) {
            float v = row_sum16(rsum[rg]);
            l_i[rg] = l_i[rg] * alpha[rg] + v;
            for (int j = 0; j < 4; j++) acc[j][rg] *= alpha[rg];
        }

        // P (C-layout) -> LDS strip (wave-private) -> A-layout fragments
        const int prow0 = wave * 16;
        for (int n = 0; n < 8; n++)
            for (int rg = 0; rg < 4; rg++) {
                int row = prow0 + quad * 4 + rg;
                int col = n * 16 + ml;
                int c = col >> 3;
                Ps[row * 128 + (((c ^ (row & 7)) & 15) << 3) + (col & 7)] = f2bf(sacc[n][rg]);
            }

        for (int kk = 0; kk < 4; kk++) {
            bf16x8 pf = *(const bf16x8*)(Ps + (prow0 + ml) * 128 +
                                         (((kk * 4 + quad) ^ (ml & 7)) << 3));
            for (int j = 0; j < 4; j++) {
                bf16x8 vf = *(const bf16x8*)(Vs[buf] + (j * 16 + ml) * 128 +
                                             (((kk * 4 + quad) ^ ml) << 3));
                acc[j] = __builtin_amdgcn_mfma_f32_16x16x32_bf16(pf, vf, acc[j], 0, 0, 0);
            }
        }

        __syncthreads();  // drains next tile's loads; orders buffer reuse
    }

    // epilogue: ctx merged [B,S,D] bf16
    int b = bh >> 4, h = bh & 15;
    for (int j = 0; j < 4; j++) {
        int d = j * 16 + ml;
        for (int rg = 0; rg < 4; rg++) {
            int srow = q0 + wave * 16 + quad * 4 + rg;
            float val = acc[j][rg] / l_i[rg];
            ctx[((size_t)(b * S_ + srow)) * D_ + h * 64 + d] = f2bf(val);
        }
    }
}

extern "C" void kernel_launch(void* const* d_in, const int* in_sizes, int n_in,
                              void* d_out, int out_size, void* d_ws, size_t ws_size,
                              hipStream_t stream) {
    const float* query = (const float*)d_in[0];
    const float* key_ = (const float*)d_in[1];
    const float* value = (const float*)d_in[2];
    // d_in[3] = mask: known causal, handled in-kernel
    const float* Wq = (const float*)d_in[4];
    const float* bq = (const float*)d_in[5];
    const float* Wk = (const float*)d_in[6];
    const float* bk = (const float*)d_in[7];
    const float* Wv = (const float*)d_in[8];
    const float* bv = (const float*)d_in[9];
    const float* Wo = (const float*)d_in[10];
    const float* bo = (const float*)d_in[11];
    float* out = (float*)d_out;

    const size_t XE = (size_t)M_ * D_;
    const size_t WE = (size_t)D_ * D_;
    char* ws = (char*)d_ws;
    unsigned short* xq = (unsigned short*)ws; ws += XE * 2;
    unsigned short* xk = (unsigned short*)ws; ws += XE * 2;
    unsigned short* xv = (unsigned short*)ws; ws += XE * 2;
    unsigned short* wqb = (unsigned short*)ws; ws += WE * 2;
    unsigned short* wkb = (unsigned short*)ws; ws += WE * 2;
    unsigned short* wvb = (unsigned short*)ws; ws += WE * 2;
    unsigned short* wob = (unsigned short*)ws; ws += WE * 2;
    unsigned short* qh = (unsigned short*)ws; ws += XE * 2;
    unsigned short* kh = (unsigned short*)ws; ws += XE * 2;
    unsigned short* vt = (unsigned short*)ws; ws += XE * 2;  // V transposed [B,H,64,S]
    unsigned short* ctx = (unsigned short*)ws; ws += XE * 2;

    cvt_all<<<dim3(XE / 1024, 7), 256, 0, stream>>>(
        query, key_, value, Wq, Wk, Wv, Wo,
        xq, xk, xv, wqb, wkb, wvb, wob, (int)XE, (int)WE);

    gemm_qkv<<<dim3(D_ / 128, M_ / 128, 3), 256, 0, stream>>>(
        xq, xk, xv, wqb, wkb, wvb, bq, bk, bv, qh, kh, vt);

    attn_kernel<<<dim3(1024), 256, 0, stream>>>(qh, kh, vt, ctx);

    gemm_out<<<dim3(D_ / 128, M_ / 128), 256, 0, stream>>>(ctx, wob, bo, out);
}

// Round 7
// 254.957 us; speedup vs baseline: 1.5068x; 1.0068x over previous
//
#include <hip/hip_runtime.h>

#define B_ 2
#define S_ 2048
#define D_ 1024
#define H_ 16
#define HD_ 64
#define M_ (B_ * S_)  // 4096

typedef __bf16 bf16x8 __attribute__((ext_vector_type(8)));
typedef float f32x4 __attribute__((ext_vector_type(4)));

__device__ inline unsigned short f2bf(float f) {
    unsigned int u = __builtin_bit_cast(unsigned int, f);
    u += 0x7fffu + ((u >> 16) & 1u);
    return (unsigned short)(u >> 16);
}

// async global->LDS, 16 bytes/lane; LDS dest = wave-uniform base + lane*16
__device__ inline void async_ld16(const unsigned short* g, unsigned short* l) {
    __builtin_amdgcn_global_load_lds(
        (const __attribute__((address_space(1))) unsigned int*)g,
        (__attribute__((address_space(3))) unsigned int*)l, 16, 0, 0);
}

// ---------------- f32 -> bf16 convert: all 7 tensors in one launch ----------------
__global__ __launch_bounds__(256) void cvt_all(
    const float* __restrict__ i0, const float* __restrict__ i1, const float* __restrict__ i2,
    const float* __restrict__ i3, const float* __restrict__ i4, const float* __restrict__ i5,
    const float* __restrict__ i6,
    unsigned short* __restrict__ o0, unsigned short* __restrict__ o1, unsigned short* __restrict__ o2,
    unsigned short* __restrict__ o3, unsigned short* __restrict__ o4, unsigned short* __restrict__ o5,
    unsigned short* __restrict__ o6, int nbig, int nsmall) {
    int z = blockIdx.y;
    const float* in = (z == 0) ? i0 : (z == 1) ? i1 : (z == 2) ? i2 : (z == 3) ? i3
                     : (z == 4) ? i4 : (z == 5) ? i5 : i6;
    unsigned short* out = (z == 0) ? o0 : (z == 1) ? o1 : (z == 2) ? o2 : (z == 3) ? o3
                         : (z == 4) ? o4 : (z == 5) ? o5 : o6;
    int n = (z < 3) ? nbig : nsmall;
    int i = (blockIdx.x * 256 + threadIdx.x) * 4;
    if (i >= n) return;
    float4 v = *(const float4*)(in + i);
    ushort4 o;
    o.x = f2bf(v.x); o.y = f2bf(v.y); o.z = f2bf(v.z); o.w = f2bf(v.w);
    *(ushort4*)(out + i) = o;
}

// ---------------- GEMM core, double-buffered: C[128x128] = A[M,K] @ W[N,K]^T ----------------
__device__ inline void gemm_compute(const unsigned short* __restrict__ A,
                                    const unsigned short* __restrict__ W,
                                    int K, int m0, int n0,
                                    unsigned short* As0, unsigned short* As1,
                                    unsigned short* Bs0, unsigned short* Bs1,
                                    f32x4 acc[4][4]) {
    const int t = threadIdx.x;
    const int lane = t & 63, wave = t >> 6;
    const int ml = lane & 15, quad = lane >> 4;
    const int wr = (wave >> 1) * 64, wc = (wave & 1) * 64;
    const int lrow = lane >> 3;
    const int gchunk = (lane & 7) ^ lrow;

    const f32x4 zero = {0.f, 0.f, 0.f, 0.f};
    for (int i = 0; i < 4; i++)
        for (int j = 0; j < 4; j++) acc[i][j] = zero;

    const int niter = K >> 6;

    auto issue = [&](int kt, unsigned short* As, unsigned short* Bs) {
        int k0 = kt << 6;
        for (int i = 0; i < 4; i++) {
            int r = wave * 32 + i * 8;
            async_ld16(A + (size_t)(m0 + r + lrow) * K + k0 + gchunk * 8, As + r * 64);
            async_ld16(W + (size_t)(n0 + r + lrow) * K + k0 + gchunk * 8, Bs + r * 64);
        }
    };

    issue(0, As0, Bs0);
    __syncthreads();

    for (int kt = 0; kt < niter; kt++) {
        unsigned short* As = (kt & 1) ? As1 : As0;
        unsigned short* Bs = (kt & 1) ? Bs1 : Bs0;
        if (kt + 1 < niter) issue(kt + 1, (kt & 1) ? As0 : As1, (kt & 1) ? Bs0 : Bs1);

        for (int kk = 0; kk < 2; ++kk) {
            bf16x8 af[4], bfr[4];
            for (int i = 0; i < 4; i++)
                af[i] = *(const bf16x8*)(As + (wr + i * 16 + ml) * 64 + (((kk * 4 + quad) ^ (ml & 7)) << 3));
            for (int j = 0; j < 4; j++)
                bfr[j] = *(const bf16x8*)(Bs + (wc + j * 16 + ml) * 64 + (((kk * 4 + quad) ^ (ml & 7)) << 3));
            for (int i = 0; i < 4; i++)
                for (int j = 0; j < 4; j++)
                    acc[i][j] = __builtin_amdgcn_mfma_f32_16x16x32_bf16(af[i], bfr[j], acc[i][j], 0, 0, 0);
        }
        __syncthreads();  // drains next tile's loads; orders buffer reuse
    }
}

// ---------------- QKV projection (z selects q/k/v) ----------------
// z=0: Q merged [M,1024], pre-scaled by 1/8.  z=1: K merged [M,1024].
// z=2: V^T [B,H,64,S].  All via LDS-transpose epilogue -> coalesced uint4 stores.
__global__ __launch_bounds__(256) void gemm_qkv(
    const unsigned short* __restrict__ xq, const unsigned short* __restrict__ xk,
    const unsigned short* __restrict__ xv,
    const unsigned short* __restrict__ wq, const unsigned short* __restrict__ wk,
    const unsigned short* __restrict__ wv,
    const float* __restrict__ bq, const float* __restrict__ bk, const float* __restrict__ bv,
    unsigned short* __restrict__ oq, unsigned short* __restrict__ ok,
    unsigned short* __restrict__ ov) {
    extern __shared__ __align__(16) unsigned short smem[];  // 64 KB dynamic
    unsigned short* As0 = smem;
    unsigned short* As1 = smem + 8192;
    unsigned short* Bs0 = smem + 16384;
    unsigned short* Bs1 = smem + 24576;

    const unsigned short *A, *W;
    const float* bias;
    unsigned short* out;
    int z = blockIdx.z;
    if (z == 0) { A = xq; W = wq; bias = bq; out = oq; }
    else if (z == 1) { A = xk; W = wk; bias = bk; out = ok; }
    else { A = xv; W = wv; bias = bv; out = ov; }

    int m0 = blockIdx.y * 128, n0 = blockIdx.x * 128;
    f32x4 acc[4][4];
    gemm_compute(A, W, D_, m0, n0, As0, As1, Bs0, Bs1, acc);

    const int t = threadIdx.x, lane = t & 63, wave = t >> 6;
    const int ml = lane & 15, quad = lane >> 4;
    const int wr = (wave >> 1) * 64, wc = (wave & 1) * 64;

    // stage C tile as bf16 into LDS (transposed for z==2), then coalesced stores
    unsigned short* Cs = smem;  // 128 x 136 (pad) = 34 KB, reuses staging space
    const float sc = (z == 0) ? 0.125f : 1.0f;
    for (int i = 0; i < 4; i++)
        for (int j = 0; j < 4; j++) {
            int col = wc + j * 16 + ml;
            float bb = bias[n0 + col];
            for (int rg = 0; rg < 4; rg++) {
                int row = wr + i * 16 + quad * 4 + rg;
                unsigned short v = f2bf((acc[i][j][rg] + bb) * sc);
                if (z < 2) Cs[row * 136 + col] = v;
                else       Cs[col * 136 + row] = v;
            }
        }
    __syncthreads();

    const int r = t >> 1, hf = t & 1;
    if (z < 2) {
        // merged [M,1024]: row m0+r, cols n0 + hf*64 + 8i
        unsigned short* dst = out + (size_t)(m0 + r) * D_ + n0 + hf * 64;
        const unsigned short* src = Cs + r * 136 + hf * 64;
        for (int i = 0; i < 8; i++)
            *(uint4*)(dst + i * 8) = *(const uint4*)(src + i * 8);
    } else {
        // V^T: row n0+r encodes (h,d); cols are s = m0 + hf*64 + 8i
        int n = n0 + r, h = n >> 6, d = n & 63;
        int b = m0 >> 11, s0 = m0 & 2047;
        unsigned short* dst = ov + ((size_t)((b * H_ + h) * 64 + d)) * S_ + s0 + hf * 64;
        const unsigned short* src = Cs + r * 136 + hf * 64;
        for (int i = 0; i < 8; i++)
            *(uint4*)(dst + i * 8) = *(const uint4*)(src + i * 8);
    }
}

// ---------------- output projection, f32 epilogue ----------------
__global__ __launch_bounds__(256) void gemm_out(const unsigned short* __restrict__ A,
                                                const unsigned short* __restrict__ W,
                                                const float* __restrict__ bias,
                                                float* __restrict__ out) {
    __shared__ unsigned short As0[128 * 64], As1[128 * 64], Bs0[128 * 64], Bs1[128 * 64];
    int m0 = blockIdx.y * 128, n0 = blockIdx.x * 128;
    f32x4 acc[4][4];
    gemm_compute(A, W, D_, m0, n0, As0, As1, Bs0, Bs1, acc);

    const int t = threadIdx.x, lane = t & 63, wave = t >> 6;
    const int ml = lane & 15, quad = lane >> 4;
    const int wr = (wave >> 1) * 64, wc = (wave & 1) * 64;
    for (int i = 0; i < 4; i++)
        for (int j = 0; j < 4; j++) {
            int n = n0 + wc + j * 16 + ml;
            float bb = bias[n];
            for (int rg = 0; rg < 4; rg++) {
                int m = m0 + wr + i * 16 + quad * 4 + rg;
                out[(size_t)m * D_ + n] = acc[i][j][rg] + bb;
            }
        }
}

// ---------------- flash attention, causal, S^T formulation ----------------
// S^T = K·Q^T via mfma(kf, qf): C-layout col=lane&15=q, row=quad*4+rg=kidx.
// Softmax stats per-lane (in-lane over 32 k-values + shfl_xor 16/32).
// P·V: A-frag is a pure in-lane repack of S^T regs (slot-permutation trick);
// B-frag reads V^T rows with the matching k-permutation (2x ds_read_b64).
__global__ __launch_bounds__(256, 2) void attn_kernel(const unsigned short* __restrict__ qm,
                                                      const unsigned short* __restrict__ km,
                                                      const unsigned short* __restrict__ vt,
                                                      unsigned short* __restrict__ ctx) {
    __shared__ unsigned short Ks[2][128 * 64];  // [k][hd], chunk-swizzled (^row&7)
    __shared__ unsigned short Vs[2][64 * 128];  // [d][k], chunk-swizzled (^d&15)

    const int qb = 31 - (blockIdx.x >> 5);
    const int bh = blockIdx.x & 31;
    const int b = bh >> 4, h = bh & 15;
    const size_t vbase = (size_t)bh * S_ * 64;
    const int t = threadIdx.x, lane = t & 63, wave = t >> 6;
    const int ml = lane & 15, quad = lane >> 4;
    const int lrow = lane >> 3;            // 0..7 (K staging row-in-group)
    const int gchunk = (lane & 7) ^ lrow;  // K swizzled source chunk
    const int vrow = lane >> 4;            // 0..3 (V staging row-in-group)
    const int q0 = qb * 64;

    // persistent Q fragments from merged layout (pre-scaled by 1/8)
    bf16x8 qf[2];
    {
        int qrow = q0 + wave * 16 + ml;
        const unsigned short* qp = qm + (size_t)(b * S_ + qrow) * D_ + h * 64;
        qf[0] = *(const bf16x8*)(qp + quad * 8);
        qf[1] = *(const bf16x8*)(qp + 32 + quad * 8);
    }

    const f32x4 zero = {0.f, 0.f, 0.f, 0.f};
    f32x4 acc[4];
    for (int j = 0; j < 4; j++) acc[j] = zero;
    float m_i = -INFINITY, l_i = 0.f;

    const int ntiles = (qb + 2) >> 1;

    // issue K/V tile kt into LDS buffer bb (8 async instrs per wave)
    auto issue_tile = [&](int kt, int bb) {
        for (int i = 0; i < 4; i++) {
            int r = wave * 32 + i * 8;  // K rows r..r+7
            async_ld16(km + (size_t)(b * S_ + kt * 128 + r + lrow) * D_ + h * 64 + gchunk * 8,
                       Ks[bb] + r * 64);
            int dd = wave * 16 + i * 4;  // V rows dd..dd+3
            int d = dd + vrow;
            async_ld16(vt + vbase + (size_t)d * S_ + kt * 128 + (((lane & 15) ^ (d & 15)) << 3),
                       Vs[bb] + dd * 128);
        }
    };

    issue_tile(0, 0);
    __syncthreads();

    for (int kt = 0; kt < ntiles; kt++) {
        const int buf = kt & 1;
        if (kt + 1 < ntiles) issue_tile(kt + 1, buf ^ 1);

        // S^T = K Q^T : 8 k-subtiles x 2 kk  (swap operands vs S)
        f32x4 sacc[8];
        for (int n = 0; n < 8; n++) sacc[n] = zero;
        for (int n = 0; n < 8; n++)
            for (int kk = 0; kk < 2; kk++) {
                bf16x8 kf = *(const bf16x8*)(Ks[buf] + (n * 16 + ml) * 64 +
                                             (((kk * 4 + quad) ^ (ml & 7)) << 3));
                sacc[n] = __builtin_amdgcn_mfma_f32_16x16x32_bf16(kf, qf[kk], sacc[n], 0, 0, 0);
            }

        // causal mask on last tile (scores already scaled via Q)
        const bool last = (kt == ntiles - 1);
        const int qidx = q0 + wave * 16 + ml;
        if (last) {
            for (int n = 0; n < 8; n++)
                for (int rg = 0; rg < 4; rg++) {
                    int kidx = kt * 128 + n * 16 + quad * 4 + rg;
                    if (kidx > qidx) sacc[n][rg] = -3.0e38f;
                }
        }

        // online softmax, per-lane (each lane owns one q column)
        float mx = sacc[0][0];
        for (int n = 0; n < 8; n++)
            for (int rg = 0; rg < 4; rg++) mx = fmaxf(mx, sacc[n][rg]);
        mx = fmaxf(mx, __shfl_xor(mx, 16));
        mx = fmaxf(mx, __shfl_xor(mx, 32));
        float mc = fmaxf(m_i, mx);
        float al = __expf(m_i - mc);
        m_i = mc;
        float rs = 0.f;
        for (int n = 0; n < 8; n++)
            for (int rg = 0; rg < 4; rg++) {
                float p = __expf(sacc[n][rg] - mc);
                sacc[n][rg] = p;
                rs += p;
            }
        rs += __shfl_xor(rs, 16);
        rs += __shfl_xor(rs, 32);
        l_i = l_i * al + rs;

        // rescale O accumulator: alpha for q-local quad*4+rg lives in lane (quad*4+rg)
        float alT[4];
        for (int rg = 0; rg < 4; rg++) alT[rg] = __shfl(al, quad * 4 + rg);
        for (int j = 0; j < 4; j++)
            for (int rg = 0; rg < 4; rg++) acc[j][rg] *= alT[rg];

        // P·V via slot-permutation: A = in-lane repack of S^T, B = permuted V rows
        for (int n2 = 0; n2 < 4; n2++) {
            union { bf16x8 v; unsigned short u[8]; } pk;
            for (int rg = 0; rg < 4; rg++) {
                pk.u[rg] = f2bf(sacc[2 * n2][rg]);
                pk.u[4 + rg] = f2bf(sacc[2 * n2 + 1][rg]);
            }
            const int c0 = 4 * n2 + (quad >> 1);
            const int qo = (quad & 1) << 2;
            for (int j = 0; j < 4; j++) {
                int row = j * 16 + ml;  // d
                union { bf16x8 v; uint2 d2[2]; } vv;
                vv.d2[0] = *(const uint2*)(Vs[buf] + row * 128 + (((c0 ^ (row & 15)) << 3) + qo));
                vv.d2[1] = *(const uint2*)(Vs[buf] + row * 128 + ((((c0 + 2) ^ (row & 15)) << 3) + qo));
                acc[j] = __builtin_amdgcn_mfma_f32_16x16x32_bf16(pk.v, vv.v, acc[j], 0, 0, 0);
            }
        }

        __syncthreads();  // drains next tile's loads; orders buffer reuse
    }

    // epilogue: ctx merged [B,S,D] bf16; l for q-local quad*4+rg via bpermute
    float lT[4];
    for (int rg = 0; rg < 4; rg++) lT[rg] = __shfl(l_i, quad * 4 + rg);
    for (int j = 0; j < 4; j++) {
        int d = j * 16 + ml;
        for (int rg = 0; rg < 4; rg++) {
            int srow = q0 + wave * 16 + quad * 4 + rg;
            float val = acc[j][rg] / lT[rg];
            ctx[((size_t)(b * S_ + srow)) * D_ + h * 64 + d] = f2bf(val);
        }
    }
}

extern "C" void kernel_launch(void* const* d_in, const int* in_sizes, int n_in,
                              void* d_out, int out_size, void* d_ws, size_t ws_size,
                              hipStream_t stream) {
    const float* query = (const float*)d_in[0];
    const float* key_ = (const float*)d_in[1];
    const float* value = (const float*)d_in[2];
    // d_in[3] = mask: known causal, handled in-kernel
    const float* Wq = (const float*)d_in[4];
    const float* bq = (const float*)d_in[5];
    const float* Wk = (const float*)d_in[6];
    const float* bk = (const float*)d_in[7];
    const float* Wv = (const float*)d_in[8];
    const float* bv = (const float*)d_in[9];
    const float* Wo = (const float*)d_in[10];
    const float* bo = (const float*)d_in[11];
    float* out = (float*)d_out;

    const size_t XE = (size_t)M_ * D_;
    const size_t WE = (size_t)D_ * D_;
    char* ws = (char*)d_ws;
    unsigned short* xq = (unsigned short*)ws; ws += XE * 2;
    unsigned short* xk = (unsigned short*)ws; ws += XE * 2;
    unsigned short* xv = (unsigned short*)ws; ws += XE * 2;
    unsigned short* wqb = (unsigned short*)ws; ws += WE * 2;
    unsigned short* wkb = (unsigned short*)ws; ws += WE * 2;
    unsigned short* wvb = (unsigned short*)ws; ws += WE * 2;
    unsigned short* wob = (unsigned short*)ws; ws += WE * 2;
    unsigned short* qmb = (unsigned short*)ws; ws += XE * 2;  // Q merged, pre-scaled
    unsigned short* kmb = (unsigned short*)ws; ws += XE * 2;  // K merged
    unsigned short* vt = (unsigned short*)ws; ws += XE * 2;   // V^T [B,H,64,S]
    unsigned short* ctx = (unsigned short*)ws; ws += XE * 2;

    cvt_all<<<dim3(XE / 1024, 7), 256, 0, stream>>>(
        query, key_, value, Wq, Wk, Wv, Wo,
        xq, xk, xv, wqb, wkb, wvb, wob, (int)XE, (int)WE);

    gemm_qkv<<<dim3(D_ / 128, M_ / 128, 3), 256, 65536, stream>>>(
        xq, xk, xv, wqb, wkb, wvb, bq, bk, bv, qmb, kmb, vt);

    attn_kernel<<<dim3(1024), 256, 0, stream>>>(qmb, kmb, vt, ctx);

    gemm_out<<<dim3(D_ / 128, M_ / 128), 256, 0, stream>>>(ctx, wob, bo, out);
}